// Round 1
// baseline (546.051 us; speedup 1.0000x reference)
//
#include <hip/hip_runtime.h>
#include <math.h>

#define T_LEN 4096
#define BATCH 4
#define NF 60
#define NBINS 33
#define TOTIN 2040   // 60 + 60*33
#define HID 256
#define NTOK (BATCH * T_LEN)   // 16384

// ---------- compile-time cos table: cos(2*pi*j/64), j=0..63 ----------
constexpr double K_PI = 3.14159265358979323846;
constexpr double tcos(double x) {
    while (x >  K_PI) x -= 2.0 * K_PI;
    while (x < -K_PI) x += 2.0 * K_PI;
    double x2 = x * x, s = 0.0, term = 1.0;
    for (int m = 0; m < 14; ++m) { s += term; term *= -x2 / ((2.0*m + 1.0) * (2.0*m + 2.0)); }
    return s;
}
struct CosTab { float v[64]; };
constexpr CosTab make_tab() {
    CosTab t{};
    for (int j = 0; j < 64; ++j) t.v[j] = (float)tcos(2.0 * K_PI * (double)j / 64.0);
    return t;
}
constexpr CosTab CT = make_tab();

// ---------- kernel 1: sliding-window DFT magnitude features ----------
// One thread per (token, feature). Window fully in registers, DFT fully
// unrolled with literal-constant twiddles (no LDS in inner loop).
// Output layout (bin-major for coalesced writes):
//   h0[tok][f]              = x[tok][f]                  (f < 60)
//   h0[tok][60 + k*60 + f]  = log1p(|rfft(window)|_k)
__global__ __launch_bounds__(256) void fft_feat_kernel(
        const float* __restrict__ x, float* __restrict__ h0) {
    const int gid = blockIdx.x * 256 + threadIdx.x;   // 0 .. 983039
    const int f   = gid % NF;
    const int tok = gid / NF;            // 0 .. 16383
    const int b   = tok >> 12;           // tok / 4096
    const int t   = tok & (T_LEN - 1);
    const float* xb = x + (size_t)b * T_LEN * NF;

    float w[64];
#pragma unroll
    for (int n = 0; n < 64; ++n) {
        int r = t + n - 32;                       // reflect pad
        r = (r < 0) ? -r : r;
        r = (r > T_LEN - 1) ? (2 * (T_LEN - 1) - r) : r;
        w[n] = xb[(size_t)r * NF + f];
    }

    // even/odd pairing: s[n] = w[n]+w[64-n], d[n] = w[n]-w[64-n]
    float s[32], d[32];
#pragma unroll
    for (int n = 1; n < 32; ++n) { s[n] = w[n] + w[64 - n]; d[n] = w[n] - w[64 - n]; }

    float* out = h0 + (size_t)tok * TOTIN;
    out[f] = w[32];   // window sample n=32 == x[t][f]  (raw-feature passthrough)

#pragma unroll
    for (int k = 0; k < NBINS; ++k) {
        // Re_k = w0 + (-1)^k w32 + sum_{n=1..31} s[n] cos(2pi k n/64)
        // Im_k = -sum_{n=1..31} d[n] sin(2pi k n/64)   (sign irrelevant for |.|)
        float re = w[0] + ((k & 1) ? -w[32] : w[32]);
        float im = 0.f;
#pragma unroll
        for (int n = 1; n < 32; ++n) {
            re = fmaf(s[n], CT.v[(k * n) & 63], re);
            im = fmaf(d[n], CT.v[(k * n + 48) & 63], im);   // cos(th+3pi/2)=sin(th)
        }
        float mag = sqrtf(re * re + im * im);
        out[60 + k * 60 + f] = log1pf(mag);
    }
}

// ---------- tiled fp32 GEMM: C[M,N] = act(A[M,K] @ B[K,N] + bias) ----------
// 64x64 tile, BK=16, 256 threads, 4x4 per thread.
// PERM_B: A columns are stored bin-major (c = 60 + k*60 + f); remap to W1's
// logical row r = 60 + f*33 + k when loading B.
template<bool PERM_B, bool RELU>
__global__ __launch_bounds__(256) void gemm_kernel(
        const float* __restrict__ A, const float* __restrict__ B,
        const float* __restrict__ bias, float* __restrict__ C,
        int M, int N, int K) {
    __shared__ float As[16][68];
    __shared__ float Bs[16][68];
    const int tid = threadIdx.x;
    const int tx = tid & 15, ty = tid >> 4;
    const int row0 = blockIdx.x * 64, col0 = blockIdx.y * 64;
    float acc[4][4] = {};

    for (int k0 = 0; k0 < K; k0 += 16) {
#pragma unroll
        for (int i = 0; i < 4; ++i) {          // A tile: 64 x 16
            int e = tid + i * 256;
            int m = e >> 4, kk = e & 15;
            int gk = k0 + kk;
            As[kk][m] = (gk < K) ? A[(size_t)(row0 + m) * K + gk] : 0.f;
        }
#pragma unroll
        for (int i = 0; i < 4; ++i) {          // B tile: 16 x 64
            int e = tid + i * 256;
            int kk = e >> 6, n = e & 63;
            int gk = k0 + kk;
            float v = 0.f;
            if (gk < K) {
                int r = gk;
                if (PERM_B && gk >= 60) { int q = gk - 60; r = 60 + (q % 60) * NBINS + (q / 60); }
                v = B[(size_t)r * N + col0 + n];
            }
            Bs[kk][n] = v;
        }
        __syncthreads();
#pragma unroll
        for (int kk = 0; kk < 16; ++kk) {
            float a[4], bv[4];
#pragma unroll
            for (int i = 0; i < 4; ++i) a[i] = As[kk][ty * 4 + i];
#pragma unroll
            for (int j = 0; j < 4; ++j) bv[j] = Bs[kk][tx * 4 + j];
#pragma unroll
            for (int i = 0; i < 4; ++i)
#pragma unroll
                for (int j = 0; j < 4; ++j)
                    acc[i][j] = fmaf(a[i], bv[j], acc[i][j]);
        }
        __syncthreads();
    }

#pragma unroll
    for (int i = 0; i < 4; ++i) {
        int m = row0 + ty * 4 + i;
#pragma unroll
        for (int j = 0; j < 4; ++j) {
            int n = col0 + tx * 4 + j;
            float v = acc[i][j] + bias[n];
            if (RELU) v = fmaxf(v, 0.f);
            C[(size_t)m * N + n] = v;
        }
    }
}

// ---------- final head: [NTOK,128] @ [128,3] + b ----------
__global__ __launch_bounds__(256) void head_kernel(
        const float* __restrict__ H, const float* __restrict__ W4,
        const float* __restrict__ b4, float* __restrict__ out) {
    __shared__ float Ws[128 * 3];
    __shared__ float bs[3];
    for (int i = threadIdx.x; i < 384; i += 256) Ws[i] = W4[i];
    if (threadIdx.x < 3) bs[threadIdx.x] = b4[threadIdx.x];
    __syncthreads();
    const int tok = blockIdx.x * 256 + threadIdx.x;
    const float* h = H + (size_t)tok * 128;
    float a0 = bs[0], a1 = bs[1], a2 = bs[2];
#pragma unroll
    for (int k = 0; k < 128; ++k) {
        float hv = h[k];
        a0 = fmaf(hv, Ws[k * 3 + 0], a0);
        a1 = fmaf(hv, Ws[k * 3 + 1], a1);
        a2 = fmaf(hv, Ws[k * 3 + 2], a2);
    }
    float* o = out + (size_t)tok * 3;
    o[0] = a0; o[1] = a1; o[2] = a2;
}

extern "C" void kernel_launch(void* const* d_in, const int* in_sizes, int n_in,
                              void* d_out, int out_size, void* d_ws, size_t ws_size,
                              hipStream_t stream) {
    (void)in_sizes; (void)n_in; (void)out_size; (void)ws_size;
    const float* x  = (const float*)d_in[0];
    const float* W1 = (const float*)d_in[1];
    const float* b1 = (const float*)d_in[2];
    const float* W2 = (const float*)d_in[3];
    const float* b2 = (const float*)d_in[4];
    const float* W3 = (const float*)d_in[5];
    const float* b3 = (const float*)d_in[6];
    const float* W4 = (const float*)d_in[7];
    const float* b4 = (const float*)d_in[8];
    float* out = (float*)d_out;

    // workspace layout (floats). H2/H3 reuse H0's region (dead after GEMM1).
    float* ws = (float*)d_ws;
    float* H0 = ws;                                   // 16384*2040
    float* H1 = H0 + (size_t)NTOK * TOTIN;            // 16384*256
    float* H2 = ws;                                   // 16384*256 (reuses H0)
    float* H3 = ws + (size_t)NTOK * HID;              // 16384*128

    fft_feat_kernel<<<NTOK * NF / 256, 256, 0, stream>>>(x, H0);

    dim3 g1(NTOK / 64, HID / 64);
    gemm_kernel<true,  true><<<g1, 256, 0, stream>>>(H0, W1, b1, H1, NTOK, HID, TOTIN);

    dim3 g2(NTOK / 64, HID / 64);
    gemm_kernel<false, true><<<g2, 256, 0, stream>>>(H1, W2, b2, H2, NTOK, HID, HID);

    dim3 g3(NTOK / 64, (HID / 2) / 64);
    gemm_kernel<false, true><<<g3, 256, 0, stream>>>(H2, W3, b3, H3, NTOK, HID / 2, HID);

    head_kernel<<<NTOK / 256, 256, 0, stream>>>(H3, W4, b4, out);
}

// Round 2
// 291.499 us; speedup vs baseline: 1.8733x; 1.8733x over previous
//
#include <hip/hip_runtime.h>
#include <math.h>

#define T_LEN 4096
#define NF 60
#define NBINS 33
#define TOTIN 2040   // 60 + 60*33
#define HID 256
#define NTOK 16384

typedef __bf16 bf16_t;
typedef bf16_t bf16x8 __attribute__((ext_vector_type(8)));
typedef float f32x4 __attribute__((ext_vector_type(4)));

// ---------- compile-time cos table: cos(2*pi*j/64), j=0..63 ----------
constexpr double K_PI = 3.14159265358979323846;
constexpr double tcos(double x) {
    while (x >  K_PI) x -= 2.0 * K_PI;
    while (x < -K_PI) x += 2.0 * K_PI;
    double x2 = x * x, s = 0.0, term = 1.0;
    for (int m = 0; m < 14; ++m) { s += term; term *= -x2 / ((2.0*m + 1.0) * (2.0*m + 2.0)); }
    return s;
}
struct CosTab { float v[64]; };
constexpr CosTab make_tab() {
    CosTab t{};
    for (int j = 0; j < 64; ++j) t.v[j] = (float)tcos(2.0 * K_PI * (double)j / 64.0);
    return t;
}
constexpr CosTab CT = make_tab();

// ---------- kernel 1: sliding-window DFT magnitude features ----------
// h0[tok][f] = x, h0[tok][60 + k*60 + f] = log1p(|rfft|_k)  (bin-major)
__global__ __launch_bounds__(256) void fft_feat_kernel(
        const float* __restrict__ x, float* __restrict__ h0) {
    const int gid = blockIdx.x * 256 + threadIdx.x;
    const int f   = gid % NF;
    const int tok = gid / NF;
    const int b   = tok >> 12;
    const int t   = tok & (T_LEN - 1);
    const float* xb = x + (size_t)b * T_LEN * NF;

    float w[64];
#pragma unroll
    for (int n = 0; n < 64; ++n) {
        int r = t + n - 32;
        r = (r < 0) ? -r : r;
        r = (r > T_LEN - 1) ? (2 * (T_LEN - 1) - r) : r;
        w[n] = xb[(size_t)r * NF + f];
    }

    float s[32], d[32];
#pragma unroll
    for (int n = 1; n < 32; ++n) { s[n] = w[n] + w[64 - n]; d[n] = w[n] - w[64 - n]; }

    float* out = h0 + (size_t)tok * TOTIN;
    out[f] = w[32];

#pragma unroll
    for (int k = 0; k < NBINS; ++k) {
        float re = w[0] + ((k & 1) ? -w[32] : w[32]);
        float im = 0.f;
#pragma unroll
        for (int n = 1; n < 32; ++n) {
            re = fmaf(s[n], CT.v[(k * n) & 63], re);
            im = fmaf(d[n], CT.v[(k * n + 48) & 63], im);
        }
        float mag = sqrtf(re * re + im * im);
        out[60 + k * 60 + f] = log1pf(mag);
    }
}

// ---------- MFMA GEMM with on-the-fly fp32 -> 2xbf16 split (3 products) ----
// C[M,N] = relu(A[M,(Kreal)] @ Wperm[Kreal,N] + bias), computed as
// Ahi*Bhi + Alo*Bhi + Ahi*Blo in f32 MFMA accumulators (~fp32 accuracy).
// Tile: BM=128, BN=64, BK=32. 4 waves, each owns 64x32 (4x2 frags 16x16).
// Kloop may exceed Kreal (tail rows of B are zero-filled; A over-read is
// harmless finite*0).
template<bool PERM>
__global__ __launch_bounds__(256, 2) void gemm3s_kernel(
        const float* __restrict__ A, const float* __restrict__ W,
        const float* __restrict__ bias, float* __restrict__ C,
        int M, int N, int lda, int Kloop, int Kreal) {
    __shared__ bf16_t Ahi[128][40];   // 40-elem rows: 80B stride, 16B aligned,
    __shared__ bf16_t Alo[128][40];   // conflict-free for b128 frag reads
    __shared__ bf16_t Bhi[64][40];
    __shared__ bf16_t Blo[64][40];

    const int tid  = threadIdx.x;
    const int row0 = blockIdx.x * 128;
    const int col0 = blockIdx.y * 64;

    // A staging: thread -> (row, 16-elem k chunk)
    const int arow = tid >> 1;
    const int akb  = (tid & 1) * 16;
    const float* aptr = A + (size_t)(row0 + arow) * lda + akb;

    // B staging: thread -> (col, 8-elem k chunk), gathered from fp32 W
    const int bn  = tid & 63;
    const int bk8 = (tid >> 6) * 8;

    const int wv   = tid >> 6;
    const int lane = tid & 63;
    const int wr = wv >> 1, wc = wv & 1;
    const int lr = lane & 15, lg = lane >> 4;

    f32x4 acc[4][2] = {};

    for (int k0 = 0; k0 < Kloop; k0 += 32) {
        // ---- global loads to regs ----
        float4 av[4];
#pragma unroll
        for (int i = 0; i < 4; ++i)
            av[i] = *(const float4*)(aptr + k0 + 4 * i);

        float bv[8];
#pragma unroll
        for (int j = 0; j < 8; ++j) {
            int gk = k0 + bk8 + j;
            float v = 0.f;
            if (gk < Kreal) {
                int r = gk;
                if (PERM && gk >= NF) {
                    int q = gk - NF;
                    r = NF + (q % NF) * NBINS + (q / NF);
                }
                v = W[(size_t)r * N + col0 + bn];
            }
            bv[j] = v;
        }

        __syncthreads();   // previous iter's frag reads done

        // ---- split + LDS write ----
        {
            const float* fa = (const float*)av;
#pragma unroll
            for (int g = 0; g < 2; ++g) {
                bf16x8 h, l;
#pragma unroll
                for (int j = 0; j < 8; ++j) {
                    float f = fa[g * 8 + j];
                    bf16_t hb = (bf16_t)f;
                    h[j] = hb;
                    l[j] = (bf16_t)(f - (float)hb);
                }
                *(bf16x8*)&Ahi[arow][akb + g * 8] = h;
                *(bf16x8*)&Alo[arow][akb + g * 8] = l;
            }
        }
        {
            bf16x8 h, l;
#pragma unroll
            for (int j = 0; j < 8; ++j) {
                float f = bv[j];
                bf16_t hb = (bf16_t)f;
                h[j] = hb;
                l[j] = (bf16_t)(f - (float)hb);
            }
            *(bf16x8*)&Bhi[bn][bk8] = h;
            *(bf16x8*)&Blo[bn][bk8] = l;
        }

        __syncthreads();   // tile staged

        // ---- fragments + 24 MFMA ----
        bf16x8 ah[4], al[4], bh[2], bl[2];
#pragma unroll
        for (int m = 0; m < 4; ++m) {
            int r = wr * 64 + m * 16 + lr;
            ah[m] = *(const bf16x8*)&Ahi[r][lg * 8];
            al[m] = *(const bf16x8*)&Alo[r][lg * 8];
        }
#pragma unroll
        for (int n = 0; n < 2; ++n) {
            int c = wc * 32 + n * 16 + lr;
            bh[n] = *(const bf16x8*)&Bhi[c][lg * 8];
            bl[n] = *(const bf16x8*)&Blo[c][lg * 8];
        }
#pragma unroll
        for (int m = 0; m < 4; ++m)
#pragma unroll
            for (int n = 0; n < 2; ++n) {
                acc[m][n] = __builtin_amdgcn_mfma_f32_16x16x32_bf16(ah[m], bh[n], acc[m][n], 0, 0, 0);
                acc[m][n] = __builtin_amdgcn_mfma_f32_16x16x32_bf16(al[m], bh[n], acc[m][n], 0, 0, 0);
                acc[m][n] = __builtin_amdgcn_mfma_f32_16x16x32_bf16(ah[m], bl[n], acc[m][n], 0, 0, 0);
            }
    }

    // ---- epilogue: bias + relu, C/D map col=lane&15, row=(lane>>4)*4+reg ----
#pragma unroll
    for (int n = 0; n < 2; ++n) {
        int col = col0 + wc * 32 + n * 16 + lr;
        float bs = bias[col];
#pragma unroll
        for (int m = 0; m < 4; ++m)
#pragma unroll
            for (int r = 0; r < 4; ++r) {
                int row = row0 + wr * 64 + m * 16 + lg * 4 + r;
                float v = acc[m][n][r] + bs;
                v = fmaxf(v, 0.f);
                C[(size_t)row * N + col] = v;
            }
    }
}

// ---------- final head: [NTOK,128] @ [128,3] + b ----------
__global__ __launch_bounds__(256) void head_kernel(
        const float* __restrict__ H, const float* __restrict__ W4,
        const float* __restrict__ b4, float* __restrict__ out) {
    __shared__ float Ws[128 * 3];
    __shared__ float bs[3];
    for (int i = threadIdx.x; i < 384; i += 256) Ws[i] = W4[i];
    if (threadIdx.x < 3) bs[threadIdx.x] = b4[threadIdx.x];
    __syncthreads();
    const int tok = blockIdx.x * 256 + threadIdx.x;
    const float* h = H + (size_t)tok * 128;
    float a0 = bs[0], a1 = bs[1], a2 = bs[2];
#pragma unroll
    for (int k = 0; k < 128; ++k) {
        float hv = h[k];
        a0 = fmaf(hv, Ws[k * 3 + 0], a0);
        a1 = fmaf(hv, Ws[k * 3 + 1], a1);
        a2 = fmaf(hv, Ws[k * 3 + 2], a2);
    }
    float* o = out + (size_t)tok * 3;
    o[0] = a0; o[1] = a1; o[2] = a2;
}

extern "C" void kernel_launch(void* const* d_in, const int* in_sizes, int n_in,
                              void* d_out, int out_size, void* d_ws, size_t ws_size,
                              hipStream_t stream) {
    (void)in_sizes; (void)n_in; (void)out_size; (void)ws_size;
    const float* x  = (const float*)d_in[0];
    const float* W1 = (const float*)d_in[1];
    const float* b1 = (const float*)d_in[2];
    const float* W2 = (const float*)d_in[3];
    const float* b2 = (const float*)d_in[4];
    const float* W3 = (const float*)d_in[5];
    const float* b3 = (const float*)d_in[6];
    const float* W4 = (const float*)d_in[7];
    const float* b4 = (const float*)d_in[8];
    float* out = (float*)d_out;

    // ws layout (floats), total = 150.5 MB (same as round-1 known-safe):
    float* ws = (float*)d_ws;
    float* H0 = ws;                                   // [16384][2040] fp32
    float* H1 = ws + (size_t)NTOK * TOTIN;            // [16384][256]
    float* H2 = ws;                                   // [16384][256]  (H0 dead)
    float* H3 = ws + (size_t)NTOK * HID;              // [16384][128]  (in old H0)

    fft_feat_kernel<<<NTOK * NF / 256, 256, 0, stream>>>(x, H0);

    // GEMM1: Kloop=2048 (pad), Kreal=2040, permuted W1
    {
        dim3 g(NTOK / 128, HID / 64);
        gemm3s_kernel<true><<<g, 256, 0, stream>>>(H0, W1, b1, H1,
                                                   NTOK, HID, TOTIN, 2048, TOTIN);
    }
    // GEMM2
    {
        dim3 g(NTOK / 128, HID / 64);
        gemm3s_kernel<false><<<g, 256, 0, stream>>>(H1, W2, b2, H2,
                                                    NTOK, HID, HID, HID, HID);
    }
    // GEMM3
    {
        dim3 g(NTOK / 128, (HID / 2) / 64);
        gemm3s_kernel<false><<<g, 256, 0, stream>>>(H2, W3, b3, H3,
                                                    NTOK, HID / 2, HID, HID, HID);
    }
    head_kernel<<<NTOK / 256, 256, 0, stream>>>(H3, W4, b4, out);
}

// Round 3
// 243.563 us; speedup vs baseline: 2.2419x; 1.1968x over previous
//
#include <hip/hip_runtime.h>
#include <math.h>

#define T_LEN 4096
#define NF 60
#define NBINS 33
#define TOTIN 2040   // 60 + 60*33
#define HID 256
#define NTOK 16384
#define MROWS (NTOK * NF)   // 983040

typedef __bf16 bf16_t;
typedef bf16_t bf16x8 __attribute__((ext_vector_type(8)));
typedef float f32x4 __attribute__((ext_vector_type(4)));

// ---------- compile-time cos table: cos(2*pi*j/64), j=0..63 ----------
constexpr double K_PI = 3.14159265358979323846;
constexpr double tcos(double x) {
    while (x >  K_PI) x -= 2.0 * K_PI;
    while (x < -K_PI) x += 2.0 * K_PI;
    double x2 = x * x, s = 0.0, term = 1.0;
    for (int m = 0; m < 14; ++m) { s += term; term *= -x2 / ((2.0*m + 1.0) * (2.0*m + 2.0)); }
    return s;
}
struct CosTab { float v[64]; };
constexpr CosTab make_tab() {
    CosTab t{};
    for (int j = 0; j < 64; ++j) t.v[j] = (float)tcos(2.0 * K_PI * (double)j / 64.0);
    return t;
}
__device__ constexpr CosTab CTd = make_tab();

__device__ __forceinline__ float log1p_fast(float x) {
    return 0.69314718055994531f * __log2f(1.0f + x);
}

// ---------- DFT matrix hi/lo bf16 tables: DFT[row][n], 64x64 ----------
// row 0..32:  cos(2*pi*row*n/64)   (re rows)
// row 33..63: sin(2*pi*(row-32)*n/64)  (im rows, sign irrelevant for |.|)
__global__ __launch_bounds__(256) void gen_dft_tab(bf16_t* __restrict__ hi,
                                                   bf16_t* __restrict__ lo) {
    const int i = blockIdx.x * 256 + threadIdx.x;   // 0..4095
    const int row = i >> 6, n = i & 63;
    float c;
    if (row < 33) c = CTd.v[(row * n) & 63];
    else          c = CTd.v[((row - 32) * n + 48) & 63];  // cos(th+3pi/2)=sin(th)
    bf16_t h = (bf16_t)c;
    hi[i] = h;
    lo[i] = (bf16_t)(c - (float)h);
}

// ---------- MFMA sliding-window DFT features ----------
// D[bin_row, m] = sum_n DFT[bin_row][n] * win[m][n],  m = tok*60 + f.
// A = DFT (from tables), B = windows (staged to LDS, 3-split bf16).
// C cols (lane&15) = m -> coalesced bin-major stores into h0.
__global__ __launch_bounds__(256) void fft_mfma_kernel(
        const float* __restrict__ x, const bf16_t* __restrict__ AhiT,
        const bf16_t* __restrict__ AloT, float* __restrict__ h0) {
    __shared__ bf16_t Bh[128][72];   // 72-elem rows: 144B stride (16B-aligned),
    __shared__ bf16_t Bl[128][72];   // 2-way-only bank aliasing on b128 ops

    const int tid  = threadIdx.x;
    const int m0   = blockIdx.x * 128;
    const int lane = tid & 63, wv = tid >> 6;
    const int lr   = lane & 15, lg = lane >> 4;

    // ---- A fragments from global tables: 4 row-frags x 2 k-steps, hi+lo ----
    bf16x8 ah[4][2], al[4][2];
#pragma unroll
    for (int rf = 0; rf < 4; ++rf)
#pragma unroll
        for (int ks = 0; ks < 2; ++ks) {
            int idx = (16 * rf + lr) * 64 + ks * 32 + lg * 8;
            ah[rf][ks] = *(const bf16x8*)&AhiT[idx];
            al[rf][ks] = *(const bf16x8*)&AloT[idx];
        }

    // ---- stage windows into LDS (hi/lo split) ----
    {
        const int sm = tid >> 1;             // local m row 0..127
        const int nh = (tid & 1) * 32;       // k half
        const int gm = m0 + sm;
        const int tok = gm / NF, f = gm - tok * NF;
        const int b = tok >> 12, t = tok & (T_LEN - 1);
        const float* xb = x + (size_t)b * T_LEN * NF + f;
#pragma unroll
        for (int c = 0; c < 4; ++c) {
            bf16x8 h, l;
#pragma unroll
            for (int j = 0; j < 8; ++j) {
                int n = nh + c * 8 + j;
                int r = t + n - 32;                      // reflect pad
                r = (r < 0) ? -r : r;
                r = (r > T_LEN - 1) ? (2 * (T_LEN - 1) - r) : r;
                float v = xb[(size_t)r * NF];
                bf16_t hb = (bf16_t)v;
                h[j] = hb;
                l[j] = (bf16_t)(v - (float)hb);
            }
            *(bf16x8*)&Bh[sm][nh + c * 8] = h;
            *(bf16x8*)&Bl[sm][nh + c * 8] = l;
        }
        // raw-feature passthrough (exact fp32)
        if ((tid & 1) == 0)
            h0[(size_t)tok * TOTIN + f] = xb[(size_t)t * NF];
    }
    __syncthreads();

    // ---- 48 MFMA per wave: all 64 bin-rows x 32 m-cols ----
    f32x4 acc[4][2] = {};
#pragma unroll
    for (int cf = 0; cf < 2; ++cf) {
        const int mrow = wv * 32 + cf * 16 + lr;
#pragma unroll
        for (int ks = 0; ks < 2; ++ks) {
            bf16x8 bh = *(const bf16x8*)&Bh[mrow][ks * 32 + lg * 8];
            bf16x8 bl = *(const bf16x8*)&Bl[mrow][ks * 32 + lg * 8];
#pragma unroll
            for (int rf = 0; rf < 4; ++rf) {
                acc[rf][cf] = __builtin_amdgcn_mfma_f32_16x16x32_bf16(ah[rf][ks], bh, acc[rf][cf], 0, 0, 0);
                acc[rf][cf] = __builtin_amdgcn_mfma_f32_16x16x32_bf16(al[rf][ks], bh, acc[rf][cf], 0, 0, 0);
                acc[rf][cf] = __builtin_amdgcn_mfma_f32_16x16x32_bf16(ah[rf][ks], bl, acc[rf][cf], 0, 0, 0);
            }
        }
    }

    // ---- epilogue: mag -> log1p -> bin-major store ----
    // C/D map: col = lane&15 (m), row-in-frag = lg*4 + r.
    // re_k: frag k/16 (k=0..31); im_k at row 32+k: frags 2,3 same lane/reg.
    // Special: frag2 reg0 lane-group lg=0 holds re_32 (row 32).
#pragma unroll
    for (int cf = 0; cf < 2; ++cf) {
        const int gm = m0 + wv * 32 + cf * 16 + lr;
        const int tok = gm / NF, f = gm - tok * NF;
        float* ob = h0 + (size_t)tok * TOTIN + 60 + f;
#pragma unroll
        for (int rf = 0; rf < 2; ++rf)
#pragma unroll
            for (int r = 0; r < 4; ++r) {
                const int k = 16 * rf + lg * 4 + r;
                float re = acc[rf][cf][r];
                float im = acc[rf + 2][cf][r];
                if (rf == 0 && r == 0 && lg == 0) {
                    ob[0]       = log1p_fast(fabsf(re));   // bin 0 (im_0 = 0)
                    ob[32 * 60] = log1p_fast(fabsf(im));   // bin 32 (slot holds re_32)
                } else {
                    ob[k * 60] = log1p_fast(sqrtf(re * re + im * im));
                }
            }
    }
}

// ---------- MFMA GEMM with on-the-fly fp32 -> 2xbf16 split (3 products) ----
template<bool PERM>
__global__ __launch_bounds__(256, 2) void gemm3s_kernel(
        const float* __restrict__ A, const float* __restrict__ W,
        const float* __restrict__ bias, float* __restrict__ C,
        int M, int N, int lda, int Kloop, int Kreal) {
    __shared__ bf16_t Ahi[128][40];
    __shared__ bf16_t Alo[128][40];
    __shared__ bf16_t Bhi[64][40];
    __shared__ bf16_t Blo[64][40];

    const int tid  = threadIdx.x;
    const int row0 = blockIdx.x * 128;
    const int col0 = blockIdx.y * 64;

    const int arow = tid >> 1;
    const int akb  = (tid & 1) * 16;
    const float* aptr = A + (size_t)(row0 + arow) * lda + akb;

    const int bn  = tid & 63;
    const int bk8 = (tid >> 6) * 8;

    const int wv   = tid >> 6;
    const int lane = tid & 63;
    const int wr = wv >> 1, wc = wv & 1;
    const int lr = lane & 15, lg = lane >> 4;

    f32x4 acc[4][2] = {};

    for (int k0 = 0; k0 < Kloop; k0 += 32) {
        float4 av[4];
#pragma unroll
        for (int i = 0; i < 4; ++i)
            av[i] = *(const float4*)(aptr + k0 + 4 * i);

        float bv[8];
#pragma unroll
        for (int j = 0; j < 8; ++j) {
            int gk = k0 + bk8 + j;
            float v = 0.f;
            if (gk < Kreal) {
                int r = gk;
                if (PERM && gk >= NF) {
                    int q = gk - NF;
                    r = NF + (q % NF) * NBINS + (q / NF);
                }
                v = W[(size_t)r * N + col0 + bn];
            }
            bv[j] = v;
        }

        __syncthreads();

        {
            const float* fa = (const float*)av;
#pragma unroll
            for (int g = 0; g < 2; ++g) {
                bf16x8 h, l;
#pragma unroll
                for (int j = 0; j < 8; ++j) {
                    float f = fa[g * 8 + j];
                    bf16_t hb = (bf16_t)f;
                    h[j] = hb;
                    l[j] = (bf16_t)(f - (float)hb);
                }
                *(bf16x8*)&Ahi[arow][akb + g * 8] = h;
                *(bf16x8*)&Alo[arow][akb + g * 8] = l;
            }
        }
        {
            bf16x8 h, l;
#pragma unroll
            for (int j = 0; j < 8; ++j) {
                float f = bv[j];
                bf16_t hb = (bf16_t)f;
                h[j] = hb;
                l[j] = (bf16_t)(f - (float)hb);
            }
            *(bf16x8*)&Bhi[bn][bk8] = h;
            *(bf16x8*)&Blo[bn][bk8] = l;
        }

        __syncthreads();

        bf16x8 ahv[4], alv[4], bhv[2], blv[2];
#pragma unroll
        for (int m = 0; m < 4; ++m) {
            int r = wr * 64 + m * 16 + lr;
            ahv[m] = *(const bf16x8*)&Ahi[r][lg * 8];
            alv[m] = *(const bf16x8*)&Alo[r][lg * 8];
        }
#pragma unroll
        for (int n = 0; n < 2; ++n) {
            int c = wc * 32 + n * 16 + lr;
            bhv[n] = *(const bf16x8*)&Bhi[c][lg * 8];
            blv[n] = *(const bf16x8*)&Blo[c][lg * 8];
        }
#pragma unroll
        for (int m = 0; m < 4; ++m)
#pragma unroll
            for (int n = 0; n < 2; ++n) {
                acc[m][n] = __builtin_amdgcn_mfma_f32_16x16x32_bf16(ahv[m], bhv[n], acc[m][n], 0, 0, 0);
                acc[m][n] = __builtin_amdgcn_mfma_f32_16x16x32_bf16(alv[m], bhv[n], acc[m][n], 0, 0, 0);
                acc[m][n] = __builtin_amdgcn_mfma_f32_16x16x32_bf16(ahv[m], blv[n], acc[m][n], 0, 0, 0);
            }
    }

#pragma unroll
    for (int n = 0; n < 2; ++n) {
        int col = col0 + wc * 32 + n * 16 + lr;
        float bs = bias[col];
#pragma unroll
        for (int m = 0; m < 4; ++m)
#pragma unroll
            for (int r = 0; r < 4; ++r) {
                int row = row0 + wr * 64 + m * 16 + lg * 4 + r;
                float v = acc[m][n][r] + bs;
                v = fmaxf(v, 0.f);
                C[(size_t)row * N + col] = v;
            }
    }
}

// ---------- final head: [NTOK,128] @ [128,3] + b ----------
__global__ __launch_bounds__(256) void head_kernel(
        const float* __restrict__ H, const float* __restrict__ W4,
        const float* __restrict__ b4, float* __restrict__ out) {
    __shared__ float Ws[128 * 3];
    __shared__ float bs[3];
    for (int i = threadIdx.x; i < 384; i += 256) Ws[i] = W4[i];
    if (threadIdx.x < 3) bs[threadIdx.x] = b4[threadIdx.x];
    __syncthreads();
    const int tok = blockIdx.x * 256 + threadIdx.x;
    const float* h = H + (size_t)tok * 128;
    float a0 = bs[0], a1 = bs[1], a2 = bs[2];
#pragma unroll
    for (int k = 0; k < 128; ++k) {
        float hv = h[k];
        a0 = fmaf(hv, Ws[k * 3 + 0], a0);
        a1 = fmaf(hv, Ws[k * 3 + 1], a1);
        a2 = fmaf(hv, Ws[k * 3 + 2], a2);
    }
    float* o = out + (size_t)tok * 3;
    o[0] = a0; o[1] = a1; o[2] = a2;
}

extern "C" void kernel_launch(void* const* d_in, const int* in_sizes, int n_in,
                              void* d_out, int out_size, void* d_ws, size_t ws_size,
                              hipStream_t stream) {
    (void)in_sizes; (void)n_in; (void)out_size; (void)ws_size;
    const float* x  = (const float*)d_in[0];
    const float* W1 = (const float*)d_in[1];
    const float* b1 = (const float*)d_in[2];
    const float* W2 = (const float*)d_in[3];
    const float* b2 = (const float*)d_in[4];
    const float* W3 = (const float*)d_in[5];
    const float* b3 = (const float*)d_in[6];
    const float* W4 = (const float*)d_in[7];
    const float* b4 = (const float*)d_in[8];
    float* out = (float*)d_out;

    // ws layout (floats), identical footprint to round 2 (150.5 MB):
    float* ws = (float*)d_ws;
    float* H0 = ws;                                   // [16384][2040] fp32
    float* H1 = ws + (size_t)NTOK * TOTIN;            // [16384][256]
    float* H2 = ws;                                   // [16384][256]  (H0 dead)
    float* H3 = ws + (size_t)NTOK * HID;              // [16384][128]

    // DFT hi/lo tables live in the LAST 16 KB of the H1 region: dead once
    // GEMM1 starts writing H1 (stream-ordered after fft_mfma_kernel).
    bf16_t* AhiT = (bf16_t*)(H1 + (size_t)NTOK * HID - 4096);
    bf16_t* AloT = AhiT + 64 * 64;

    gen_dft_tab<<<16, 256, 0, stream>>>(AhiT, AloT);
    fft_mfma_kernel<<<MROWS / 128, 256, 0, stream>>>(x, AhiT, AloT, H0);

    {   // GEMM1: Kloop=2048 (pad), Kreal=2040, permuted W1
        dim3 g(NTOK / 128, HID / 64);
        gemm3s_kernel<true><<<g, 256, 0, stream>>>(H0, W1, b1, H1,
                                                   NTOK, HID, TOTIN, 2048, TOTIN);
    }
    {   // GEMM2
        dim3 g(NTOK / 128, HID / 64);
        gemm3s_kernel<false><<<g, 256, 0, stream>>>(H1, W2, b2, H2,
                                                    NTOK, HID, HID, HID, HID);
    }
    {   // GEMM3
        dim3 g(NTOK / 128, (HID / 2) / 64);
        gemm3s_kernel<false><<<g, 256, 0, stream>>>(H2, W3, b3, H3,
                                                    NTOK, HID / 2, HID, HID, HID);
    }
    head_kernel<<<NTOK / 256, 256, 0, stream>>>(H3, W4, b4, out);
}

// Round 5
// 211.771 us; speedup vs baseline: 2.5785x; 1.1501x over previous
//
#include <hip/hip_runtime.h>
#include <math.h>

#define T_LEN 4096
#define NF 60
#define NBINS 33
#define TOTIN 2040   // 60 + 60*33
#define KPAD 2048
#define HID 256
#define NTOK 16384
#define MROWS (NTOK * NF)   // 983040

typedef __bf16 bf16_t;
typedef bf16_t bf16x8 __attribute__((ext_vector_type(8)));
typedef float f32x4 __attribute__((ext_vector_type(4)));

// ---------- compile-time cos table: cos(2*pi*j/64), j=0..63 ----------
constexpr double K_PI = 3.14159265358979323846;
constexpr double tcos(double x) {
    while (x >  K_PI) x -= 2.0 * K_PI;
    while (x < -K_PI) x += 2.0 * K_PI;
    double x2 = x * x, s = 0.0, term = 1.0;
    for (int m = 0; m < 14; ++m) { s += term; term *= -x2 / ((2.0*m + 1.0) * (2.0*m + 2.0)); }
    return s;
}
struct CosTab { float v[64]; };
constexpr CosTab make_tab() {
    CosTab t{};
    for (int j = 0; j < 64; ++j) t.v[j] = (float)tcos(2.0 * K_PI * (double)j / 64.0);
    return t;
}
__device__ constexpr CosTab CTd = make_tab();

__device__ __forceinline__ float log1p_fast(float x) {
    return 0.69314718055994531f * __log2f(1.0f + x);
}
__device__ __forceinline__ void split_bf16(float v, bf16_t& h, bf16_t& l) {
    h = (bf16_t)v;
    l = (bf16_t)(v - (float)h);
}

// ---------- one-time prep: DFT tables + pre-split/pre-transposed weights ----
// dft:  [64][64]   row 0..32 = cos rows, 33..63 = sin rows
// W1T:  [256][2048] bf16 hi/lo, W1T[j][gk] = W1[perm(gk)][j], gk>=2040 -> 0
// W2T:  [256][256]  W2T[j][k] = W2[k][j]
// W3T:  [128][256]  W3T[j][k] = W3[k][j]
__global__ __launch_bounds__(256) void prep_kernel(
        const float* __restrict__ W1, const float* __restrict__ W2,
        const float* __restrict__ W3,
        bf16_t* __restrict__ dftHi, bf16_t* __restrict__ dftLo,
        bf16_t* __restrict__ W1Thi, bf16_t* __restrict__ W1Tlo,
        bf16_t* __restrict__ W2Thi, bf16_t* __restrict__ W2Tlo,
        bf16_t* __restrict__ W3Thi, bf16_t* __restrict__ W3Tlo) {
    int i = blockIdx.x * 256 + threadIdx.x;
    if (i < 4096) {
        int row = i >> 6, n = i & 63;
        float c = (row < 33) ? CTd.v[(row * n) & 63]
                             : CTd.v[((row - 32) * n + 48) & 63];
        bf16_t h, l; split_bf16(c, h, l);
        dftHi[i] = h; dftLo[i] = l;
        return;
    }
    i -= 4096;
    if (i < 256 * KPAD) {
        int gk = i & (KPAD - 1);
        int j  = i >> 11;
        float v = 0.f;
        if (gk < TOTIN) {
            int r = gk;
            if (gk >= NF) { int q = gk - NF; r = NF + (q % NF) * NBINS + (q / NF); }
            v = W1[(size_t)r * HID + j];
        }
        bf16_t h, l; split_bf16(v, h, l);
        W1Thi[i] = h; W1Tlo[i] = l;
        return;
    }
    i -= 256 * KPAD;
    if (i < 256 * 256) {
        int k = i & 255, j = i >> 8;
        bf16_t h, l; split_bf16(W2[(size_t)k * HID + j], h, l);
        W2Thi[i] = h; W2Tlo[i] = l;
        return;
    }
    i -= 256 * 256;
    if (i < 128 * 256) {
        int k = i & 255, j = i >> 8;
        bf16_t h, l; split_bf16(W3[(size_t)k * 128 + j], h, l);
        W3Thi[i] = h; W3Tlo[i] = l;
        return;
    }
}

// ---------- MFMA sliding-window DFT features -> pre-split bf16 H0 ----------
__global__ __launch_bounds__(256) void fft_mfma_kernel(
        const float* __restrict__ x, const bf16_t* __restrict__ AhiT,
        const bf16_t* __restrict__ AloT,
        bf16_t* __restrict__ H0hi, bf16_t* __restrict__ H0lo) {
    __shared__ bf16_t Bh[128][72];
    __shared__ bf16_t Bl[128][72];

    const int tid  = threadIdx.x;
    const int m0   = blockIdx.x * 128;
    const int lane = tid & 63, wv = tid >> 6;
    const int lr   = lane & 15, lg = lane >> 4;

    // A fragments from global tables (L2-resident)
    bf16x8 ah[4][2], al[4][2];
#pragma unroll
    for (int rf = 0; rf < 4; ++rf)
#pragma unroll
        for (int ks = 0; ks < 2; ++ks) {
            int idx = (16 * rf + lr) * 64 + ks * 32 + lg * 8;
            ah[rf][ks] = *(const bf16x8*)&AhiT[idx];
            al[rf][ks] = *(const bf16x8*)&AloT[idx];
        }

    // stage windows into LDS (hi/lo split)
    {
        const int sm = tid >> 1;
        const int nh = (tid & 1) * 32;
        const int gm = m0 + sm;
        const int tok = gm / NF, f = gm - tok * NF;
        const int b = tok >> 12, t = tok & (T_LEN - 1);
        const float* xb = x + (size_t)b * T_LEN * NF + f;
#pragma unroll
        for (int c = 0; c < 4; ++c) {
            bf16x8 h, l;
#pragma unroll
            for (int j = 0; j < 8; ++j) {
                int n = nh + c * 8 + j;
                int r = t + n - 32;
                r = (r < 0) ? -r : r;
                r = (r > T_LEN - 1) ? (2 * (T_LEN - 1) - r) : r;
                float v = xb[(size_t)r * NF];
                bf16_t hh, ll;
                split_bf16(v, hh, ll);
                h[j] = hh; l[j] = ll;
            }
            *(bf16x8*)&Bh[sm][nh + c * 8] = h;
            *(bf16x8*)&Bl[sm][nh + c * 8] = l;
        }
        if ((tid & 1) == 0) {
            // raw-feature passthrough (split)
            bf16_t h, l; split_bf16(xb[(size_t)t * NF], h, l);
            H0hi[(size_t)tok * KPAD + f] = h;
            H0lo[(size_t)tok * KPAD + f] = l;
            // zero K-pad cols (once per token, by its f==0 owner)
            if (f == 0) {
                bf16x8 z = {};
                *(bf16x8*)&H0hi[(size_t)tok * KPAD + TOTIN] = z;
                *(bf16x8*)&H0lo[(size_t)tok * KPAD + TOTIN] = z;
            }
        }
    }
    __syncthreads();

    // 48 MFMA per wave
    f32x4 acc[4][2] = {};
#pragma unroll
    for (int cf = 0; cf < 2; ++cf) {
        const int mrow = wv * 32 + cf * 16 + lr;
#pragma unroll
        for (int ks = 0; ks < 2; ++ks) {
            bf16x8 bh = *(const bf16x8*)&Bh[mrow][ks * 32 + lg * 8];
            bf16x8 bl = *(const bf16x8*)&Bl[mrow][ks * 32 + lg * 8];
#pragma unroll
            for (int rf = 0; rf < 4; ++rf) {
                acc[rf][cf] = __builtin_amdgcn_mfma_f32_16x16x32_bf16(ah[rf][ks], bh, acc[rf][cf], 0, 0, 0);
                acc[rf][cf] = __builtin_amdgcn_mfma_f32_16x16x32_bf16(al[rf][ks], bh, acc[rf][cf], 0, 0, 0);
                acc[rf][cf] = __builtin_amdgcn_mfma_f32_16x16x32_bf16(ah[rf][ks], bl, acc[rf][cf], 0, 0, 0);
            }
        }
    }

    // epilogue: mag -> log1p -> split -> bin-major bf16 stores
#pragma unroll
    for (int cf = 0; cf < 2; ++cf) {
        const int gm = m0 + wv * 32 + cf * 16 + lr;
        const int tok = gm / NF, f = gm - tok * NF;
        bf16_t* obh = H0hi + (size_t)tok * KPAD + 60 + f;
        bf16_t* obl = H0lo + (size_t)tok * KPAD + 60 + f;
#pragma unroll
        for (int rf = 0; rf < 2; ++rf)
#pragma unroll
            for (int r = 0; r < 4; ++r) {
                const int k = 16 * rf + lg * 4 + r;
                float re = acc[rf][cf][r];
                float im = acc[rf + 2][cf][r];
                if (rf == 0 && r == 0 && lg == 0) {
                    bf16_t h, l;
                    split_bf16(log1p_fast(fabsf(re)), h, l);
                    obh[0] = h; obl[0] = l;
                    split_bf16(log1p_fast(fabsf(im)), h, l);
                    obh[32 * 60] = h; obl[32 * 60] = l;
                } else {
                    bf16_t h, l;
                    split_bf16(log1p_fast(sqrtf(re * re + im * im)), h, l);
                    obh[k * 60] = h; obl[k * 60] = l;
                }
            }
    }
}

// ---------- MFMA GEMM, pre-split bf16 inputs, 3-product fp32-accurate ------
// C = relu(A @ B + bias); A: [M][lda] hi/lo, BT: [N][ldb] hi/lo (transposed).
// OUT_SPLIT: write Chi/Clo bf16 pair; else fp32 Cf.
template<bool OUT_SPLIT>
__global__ __launch_bounds__(256, 2) void gemm_bf16pre(
        const bf16_t* __restrict__ Ahi, const bf16_t* __restrict__ Alo, int lda,
        const bf16_t* __restrict__ BThi, const bf16_t* __restrict__ BTlo, int ldb,
        const float* __restrict__ bias,
        bf16_t* __restrict__ Chi, bf16_t* __restrict__ Clo,
        float* __restrict__ Cf, int N, int K) {
    __shared__ bf16_t Ah[128][40];
    __shared__ bf16_t Al[128][40];
    __shared__ bf16_t Bh[64][40];
    __shared__ bf16_t Bl[64][40];

    const int tid  = threadIdx.x;
    const int row0 = blockIdx.x * 128;
    const int col0 = blockIdx.y * 64;

    const int arow = tid >> 1, ak = (tid & 1) * 16;
    const int bcol = tid >> 2, bk = (tid & 3) * 8;
    const bf16_t* aph = Ahi + (size_t)(row0 + arow) * lda + ak;
    const bf16_t* apl = Alo + (size_t)(row0 + arow) * lda + ak;
    const bf16_t* bph = BThi + (size_t)(col0 + bcol) * ldb + bk;
    const bf16_t* bpl = BTlo + (size_t)(col0 + bcol) * ldb + bk;

    const int wv = tid >> 6, lane = tid & 63;
    const int wr = wv >> 1, wc = wv & 1;
    const int lr = lane & 15, lg = lane >> 4;

    f32x4 acc[4][2] = {};

    for (int k0 = 0; k0 < K; k0 += 32) {
        bf16x8 a0h = *(const bf16x8*)(aph + k0);
        bf16x8 a1h = *(const bf16x8*)(aph + k0 + 8);
        bf16x8 a0l = *(const bf16x8*)(apl + k0);
        bf16x8 a1l = *(const bf16x8*)(apl + k0 + 8);
        bf16x8 b0h = *(const bf16x8*)(bph + k0);
        bf16x8 b0l = *(const bf16x8*)(bpl + k0);

        __syncthreads();   // previous iter's frag reads done

        *(bf16x8*)&Ah[arow][ak]     = a0h;
        *(bf16x8*)&Ah[arow][ak + 8] = a1h;
        *(bf16x8*)&Al[arow][ak]     = a0l;
        *(bf16x8*)&Al[arow][ak + 8] = a1l;
        *(bf16x8*)&Bh[bcol][bk]     = b0h;
        *(bf16x8*)&Bl[bcol][bk]     = b0l;

        __syncthreads();   // tile staged

        bf16x8 ahv[4], alv[4], bhv[2], blv[2];
#pragma unroll
        for (int m = 0; m < 4; ++m) {
            int r = wr * 64 + m * 16 + lr;
            ahv[m] = *(const bf16x8*)&Ah[r][lg * 8];
            alv[m] = *(const bf16x8*)&Al[r][lg * 8];
        }
#pragma unroll
        for (int n = 0; n < 2; ++n) {
            int c = wc * 32 + n * 16 + lr;
            bhv[n] = *(const bf16x8*)&Bh[c][lg * 8];
            blv[n] = *(const bf16x8*)&Bl[c][lg * 8];
        }
#pragma unroll
        for (int m = 0; m < 4; ++m)
#pragma unroll
            for (int n = 0; n < 2; ++n) {
                acc[m][n] = __builtin_amdgcn_mfma_f32_16x16x32_bf16(ahv[m], bhv[n], acc[m][n], 0, 0, 0);
                acc[m][n] = __builtin_amdgcn_mfma_f32_16x16x32_bf16(alv[m], bhv[n], acc[m][n], 0, 0, 0);
                acc[m][n] = __builtin_amdgcn_mfma_f32_16x16x32_bf16(ahv[m], blv[n], acc[m][n], 0, 0, 0);
            }
    }

#pragma unroll
    for (int n = 0; n < 2; ++n) {
        int col = col0 + wc * 32 + n * 16 + lr;
        float bs = bias[col];
#pragma unroll
        for (int m = 0; m < 4; ++m)
#pragma unroll
            for (int r = 0; r < 4; ++r) {
                int row = row0 + wr * 64 + m * 16 + lg * 4 + r;
                float v = fmaxf(acc[m][n][r] + bs, 0.f);
                if (OUT_SPLIT) {
                    bf16_t h, l; split_bf16(v, h, l);
                    Chi[(size_t)row * N + col] = h;
                    Clo[(size_t)row * N + col] = l;
                } else {
                    Cf[(size_t)row * N + col] = v;
                }
            }
    }
}

// ---------- final head: [NTOK,128] @ [128,3] + b ----------
__global__ __launch_bounds__(256) void head_kernel(
        const float* __restrict__ H, const float* __restrict__ W4,
        const float* __restrict__ b4, float* __restrict__ out) {
    __shared__ float Ws[128 * 3];
    __shared__ float bs[3];
    for (int i = threadIdx.x; i < 384; i += 256) Ws[i] = W4[i];
    if (threadIdx.x < 3) bs[threadIdx.x] = b4[threadIdx.x];
    __syncthreads();
    const int tok = blockIdx.x * 256 + threadIdx.x;
    const float* h = H + (size_t)tok * 128;
    float a0 = bs[0], a1 = bs[1], a2 = bs[2];
#pragma unroll
    for (int k = 0; k < 128; ++k) {
        float hv = h[k];
        a0 = fmaf(hv, Ws[k * 3 + 0], a0);
        a1 = fmaf(hv, Ws[k * 3 + 1], a1);
        a2 = fmaf(hv, Ws[k * 3 + 2], a2);
    }
    float* o = out + (size_t)tok * 3;
    o[0] = a0; o[1] = a1; o[2] = a2;
}

extern "C" void kernel_launch(void* const* d_in, const int* in_sizes, int n_in,
                              void* d_out, int out_size, void* d_ws, size_t ws_size,
                              hipStream_t stream) {
    (void)in_sizes; (void)n_in; (void)out_size; (void)ws_size;
    const float* x  = (const float*)d_in[0];
    const float* W1 = (const float*)d_in[1];
    const float* b1 = (const float*)d_in[2];
    const float* W2 = (const float*)d_in[3];
    const float* b2 = (const float*)d_in[4];
    const float* W3 = (const float*)d_in[5];
    const float* b3 = (const float*)d_in[6];
    const float* W4 = (const float*)d_in[7];
    const float* b4 = (const float*)d_in[8];
    float* out = (float*)d_out;

    // ws layout (bytes), total ~146.5 MB (< round-1's 150.5 MB known-safe)
    char* w = (char*)d_ws;
    bf16_t* H0hi  = (bf16_t*)(w);                                  // 64 MB
    bf16_t* H0lo  = (bf16_t*)(w + (size_t)64 * 1024 * 1024);       // 64 MB
    bf16_t* H1hi  = (bf16_t*)(w + (size_t)128 * 1024 * 1024);      // 8 MB
    bf16_t* H1lo  = (bf16_t*)(w + (size_t)136 * 1024 * 1024);      // 8 MB
    bf16_t* W1Thi = (bf16_t*)(w + (size_t)144 * 1024 * 1024);      // 1 MB
    bf16_t* W1Tlo = (bf16_t*)(w + (size_t)145 * 1024 * 1024);      // 1 MB
    bf16_t* W2Thi = (bf16_t*)(w + (size_t)146 * 1024 * 1024);      // 128 KB
    bf16_t* W2Tlo = W2Thi + 256 * 256;
    bf16_t* W3Thi = W2Tlo + 256 * 256;                             // 64 KB
    bf16_t* W3Tlo = W3Thi + 128 * 256;
    bf16_t* dftHi = W3Tlo + 128 * 256;                             // 8 KB
    bf16_t* dftLo = dftHi + 64 * 64;
    // reuse H0 region once it is dead (H0 dead after GEMM1):
    bf16_t* H2hi  = (bf16_t*)(w);                                  // 8 MB
    bf16_t* H2lo  = (bf16_t*)(w + (size_t)8 * 1024 * 1024);        // 8 MB
    float*  H3    = (float*) (w + (size_t)16 * 1024 * 1024);       // 8 MB

    prep_kernel<<<2448, 256, 0, stream>>>(W1, W2, W3, dftHi, dftLo,
                                          W1Thi, W1Tlo, W2Thi, W2Tlo, W3Thi, W3Tlo);
    fft_mfma_kernel<<<MROWS / 128, 256, 0, stream>>>(x, dftHi, dftLo, H0hi, H0lo);

    {   // GEMM1: [16384,2048]x[2048,256]
        dim3 g(NTOK / 128, HID / 64);
        gemm_bf16pre<true><<<g, 256, 0, stream>>>(H0hi, H0lo, KPAD,
                                                  W1Thi, W1Tlo, KPAD,
                                                  b1, H1hi, H1lo, nullptr, HID, KPAD);
    }
    {   // GEMM2: [16384,256]x[256,256]
        dim3 g(NTOK / 128, HID / 64);
        gemm_bf16pre<true><<<g, 256, 0, stream>>>(H1hi, H1lo, HID,
                                                  W2Thi, W2Tlo, HID,
                                                  b2, H2hi, H2lo, nullptr, HID, HID);
    }
    {   // GEMM3: [16384,256]x[256,128]
        dim3 g(NTOK / 128, (HID / 2) / 64);
        gemm_bf16pre<false><<<g, 256, 0, stream>>>(H2hi, H2lo, HID,
                                                   W3Thi, W3Tlo, HID,
                                                   b3, nullptr, nullptr, H3, HID / 2, HID);
    }
    head_kernel<<<NTOK / 256, 256, 0, stream>>>(H3, W4, b4, out);
}

// Round 6
// 167.258 us; speedup vs baseline: 3.2647x; 1.2661x over previous
//
#include <hip/hip_runtime.h>
#include <math.h>

#define T_LEN 4096
#define NF 60
#define NBINS 33
#define TOTIN 2040   // 60 + 60*33
#define KPAD 2048
#define HID 256
#define NTOK 16384
#define MROWS (NTOK * NF)   // 983040

typedef _Float16 half_t;
typedef half_t half8 __attribute__((ext_vector_type(8)));
typedef float f32x4 __attribute__((ext_vector_type(4)));

// ---------- compile-time cos table: cos(2*pi*j/64), j=0..63 ----------
constexpr double K_PI = 3.14159265358979323846;
constexpr double tcos(double x) {
    while (x >  K_PI) x -= 2.0 * K_PI;
    while (x < -K_PI) x += 2.0 * K_PI;
    double x2 = x * x, s = 0.0, term = 1.0;
    for (int m = 0; m < 14; ++m) { s += term; term *= -x2 / ((2.0*m + 1.0) * (2.0*m + 2.0)); }
    return s;
}
struct CosTab { float v[64]; };
constexpr CosTab make_tab() {
    CosTab t{};
    for (int j = 0; j < 64; ++j) t.v[j] = (float)tcos(2.0 * K_PI * (double)j / 64.0);
    return t;
}
__device__ constexpr CosTab CTd = make_tab();

__device__ __forceinline__ float log1p_fast(float x) {
    return 0.69314718055994531f * __log2f(1.0f + x);
}
__device__ __forceinline__ void split_f16(float v, half_t& h, half_t& l) {
    h = (half_t)v;
    l = (half_t)(v - (float)h);
}

// ---------- one-time prep: fp16 DFT hi/lo tables + fp16 weights ----------
// dft:  [64][64]  rows 0..32 = cos(2pi*r*n/64), rows 33..63 = sin rows
// W1T:  [256][2048] fp16, W1T[j][gk] = W1[perm(gk)][j], gk>=2040 -> 0
// W2T:  [256][256]  fp16 transposed; W3T: [128][256] fp16 transposed
__global__ __launch_bounds__(256) void prep_kernel(
        const float* __restrict__ W1, const float* __restrict__ W2,
        const float* __restrict__ W3,
        half_t* __restrict__ dftHi, half_t* __restrict__ dftLo,
        half_t* __restrict__ W1T, half_t* __restrict__ W2T,
        half_t* __restrict__ W3T) {
    int i = blockIdx.x * 256 + threadIdx.x;
    if (i < 4096) {
        int row = i >> 6, n = i & 63;
        float c = (row < 33) ? CTd.v[(row * n) & 63]
                             : CTd.v[((row - 32) * n + 48) & 63];
        half_t h, l; split_f16(c, h, l);
        dftHi[i] = h; dftLo[i] = l;
        return;
    }
    i -= 4096;
    if (i < 256 * KPAD) {
        int gk = i & (KPAD - 1);
        float v = 0.f;
        if (gk < TOTIN) {
            int j = i >> 11;
            int r = gk;
            if (gk >= NF) { int q = gk - NF; r = NF + (q % NF) * NBINS + (q / NF); }
            v = W1[(size_t)r * HID + j];
        }
        W1T[i] = (half_t)v;
        return;
    }
    i -= 256 * KPAD;
    if (i < 256 * 256) {
        int k = i & 255, j = i >> 8;
        W2T[i] = (half_t)W2[(size_t)k * HID + j];
        return;
    }
    i -= 256 * 256;
    if (i < 128 * 256) {
        int k = i & 255, j = i >> 8;
        W3T[i] = (half_t)W3[(size_t)k * 128 + j];
    }
}

// ---------- MFMA sliding-window DFT features -> fp16 H0 ----------
// D[bin_row, m] = sum_n DFT[row][n]*win[m][n], m = tok*60+f.
// DFT uses fp16 hi/lo 3-product split (residual ~2^-22, unbiased).
__global__ __launch_bounds__(256) void fft_mfma_kernel(
        const float* __restrict__ x, const half_t* __restrict__ AhiT,
        const half_t* __restrict__ AloT, half_t* __restrict__ H0) {
    __shared__ half_t Bh[128][72];   // 144B rows: 2-way-only bank aliasing
    __shared__ half_t Bl[128][72];

    const int tid  = threadIdx.x;
    const int m0   = blockIdx.x * 128;
    const int lane = tid & 63, wv = tid >> 6;
    const int lr   = lane & 15, lg = lane >> 4;

    // A fragments from global tables (L2-resident)
    half8 ah[4][2], al[4][2];
#pragma unroll
    for (int rf = 0; rf < 4; ++rf)
#pragma unroll
        for (int ks = 0; ks < 2; ++ks) {
            int idx = (16 * rf + lr) * 64 + ks * 32 + lg * 8;
            ah[rf][ks] = *(const half8*)&AhiT[idx];
            al[rf][ks] = *(const half8*)&AloT[idx];
        }

    // stage windows into LDS (fp16 hi/lo split)
    {
        const int sm = tid >> 1;
        const int nh = (tid & 1) * 32;
        const int gm = m0 + sm;
        const int tok = gm / NF, f = gm - tok * NF;
        const int b = tok >> 12, t = tok & (T_LEN - 1);
        const float* xb = x + (size_t)b * T_LEN * NF + f;
#pragma unroll
        for (int c = 0; c < 4; ++c) {
            half8 h, l;
#pragma unroll
            for (int j = 0; j < 8; ++j) {
                int n = nh + c * 8 + j;
                int r = t + n - 32;
                r = (r < 0) ? -r : r;
                r = (r > T_LEN - 1) ? (2 * (T_LEN - 1) - r) : r;
                float v = xb[(size_t)r * NF];
                half_t hh, ll;
                split_f16(v, hh, ll);
                h[j] = hh; l[j] = ll;
            }
            *(half8*)&Bh[sm][nh + c * 8] = h;
            *(half8*)&Bl[sm][nh + c * 8] = l;
        }
        if ((tid & 1) == 0) {
            // raw-feature passthrough (fp16)
            H0[(size_t)tok * KPAD + f] = (half_t)xb[(size_t)t * NF];
            // zero K-pad cols (once per token, by its f==0 owner)
            if (f == 0) {
                half8 z = {};
                *(half8*)&H0[(size_t)tok * KPAD + TOTIN] = z;
            }
        }
    }
    __syncthreads();

    // 48 MFMA per wave (3-product split)
    f32x4 acc[4][2] = {};
#pragma unroll
    for (int cf = 0; cf < 2; ++cf) {
        const int mrow = wv * 32 + cf * 16 + lr;
#pragma unroll
        for (int ks = 0; ks < 2; ++ks) {
            half8 bh = *(const half8*)&Bh[mrow][ks * 32 + lg * 8];
            half8 bl = *(const half8*)&Bl[mrow][ks * 32 + lg * 8];
#pragma unroll
            for (int rf = 0; rf < 4; ++rf) {
                acc[rf][cf] = __builtin_amdgcn_mfma_f32_16x16x32_f16(ah[rf][ks], bh, acc[rf][cf], 0, 0, 0);
                acc[rf][cf] = __builtin_amdgcn_mfma_f32_16x16x32_f16(al[rf][ks], bh, acc[rf][cf], 0, 0, 0);
                acc[rf][cf] = __builtin_amdgcn_mfma_f32_16x16x32_f16(ah[rf][ks], bl, acc[rf][cf], 0, 0, 0);
            }
        }
    }

    // epilogue: mag -> log1p -> fp16 bin-major store
    // C/D map: col = lane&15 (m), row-in-frag = lg*4 + r.
    // re_k in frag k/16 (k=0..31); im_k (row 32+k) in frags 2,3 same lane/reg.
    // frag2 reg0 lg=0 holds re_32.
#pragma unroll
    for (int cf = 0; cf < 2; ++cf) {
        const int gm = m0 + wv * 32 + cf * 16 + lr;
        const int tok = gm / NF, f = gm - tok * NF;
        half_t* ob = H0 + (size_t)tok * KPAD + 60 + f;
#pragma unroll
        for (int rf = 0; rf < 2; ++rf)
#pragma unroll
            for (int r = 0; r < 4; ++r) {
                const int k = 16 * rf + lg * 4 + r;
                float re = acc[rf][cf][r];
                float im = acc[rf + 2][cf][r];
                if (rf == 0 && r == 0 && lg == 0) {
                    ob[0]       = (half_t)log1p_fast(fabsf(re));   // bin 0
                    ob[32 * 60] = (half_t)log1p_fast(fabsf(im));   // bin 32 (re_32)
                } else {
                    ob[k * 60] = (half_t)log1p_fast(sqrtf(re * re + im * im));
                }
            }
    }
}

// ---------- fp16 single-product MFMA GEMM ----------
// C[M,N] = relu(A[M,K] @ BT^T + bias). BM=64, BN=N (A read once, B L2-resident).
// grid = (M/64, 1). 4 waves; wave wv owns all 64 rows x cols [wv*BN/4, +BN/4).
template<int BN, bool OUT_F32>
__global__ __launch_bounds__(256, 2) void gemm_f16(
        const half_t* __restrict__ A, int lda,
        const half_t* __restrict__ BT, int ldb,
        const float* __restrict__ bias,
        half_t* __restrict__ Ch, float* __restrict__ Cf,
        int N, int K) {
    constexpr int BM = 64;
    constexpr int NFR = BN / 64;          // n-frags per wave: 4 or 2
    constexpr int BUNITS = BN * 8 / 256;  // half8 B-units per thread
    __shared__ half_t As[BM][72];
    __shared__ half_t Bs[BN][72];

    const int tid  = threadIdx.x;
    const int row0 = blockIdx.x * BM;
    const int wv = tid >> 6, lane = tid & 63;
    const int lr = lane & 15, lg = lane >> 4;

    const int arow = tid >> 2, ak = (tid & 3) * 16;
    const half_t* ap = A + (size_t)(row0 + arow) * lda + ak;

    f32x4 acc[4][NFR] = {};

    for (int k0 = 0; k0 < K; k0 += 64) {
        half8 av0 = *(const half8*)(ap + k0);
        half8 av1 = *(const half8*)(ap + k0 + 8);
        half8 bv[BUNITS];
#pragma unroll
        for (int u = 0; u < BUNITS; ++u) {
            int e = tid + u * 256;
            int n = e >> 3, c8 = (e & 7) * 8;
            bv[u] = *(const half8*)(BT + (size_t)n * ldb + k0 + c8);
        }

        __syncthreads();   // previous iter's frag reads done

        *(half8*)&As[arow][ak]     = av0;
        *(half8*)&As[arow][ak + 8] = av1;
#pragma unroll
        for (int u = 0; u < BUNITS; ++u) {
            int e = tid + u * 256;
            int n = e >> 3, c8 = (e & 7) * 8;
            *(half8*)&Bs[n][c8] = bv[u];
        }

        __syncthreads();   // tile staged

#pragma unroll
        for (int ks = 0; ks < 2; ++ks) {
            half8 af[4], bf[NFR];
#pragma unroll
            for (int mf = 0; mf < 4; ++mf)
                af[mf] = *(const half8*)&As[mf * 16 + lr][ks * 32 + lg * 8];
#pragma unroll
            for (int nf = 0; nf < NFR; ++nf)
                bf[nf] = *(const half8*)&Bs[wv * (16 * NFR) + nf * 16 + lr][ks * 32 + lg * 8];
#pragma unroll
            for (int mf = 0; mf < 4; ++mf)
#pragma unroll
                for (int nf = 0; nf < NFR; ++nf)
                    acc[mf][nf] = __builtin_amdgcn_mfma_f32_16x16x32_f16(af[mf], bf[nf], acc[mf][nf], 0, 0, 0);
        }
    }

    // epilogue: bias + relu; C/D map col=lane&15, row=(lane>>4)*4+reg
#pragma unroll
    for (int nf = 0; nf < NFR; ++nf) {
        int col = wv * (16 * NFR) + nf * 16 + lr;
        float bs = bias[col];
#pragma unroll
        for (int mf = 0; mf < 4; ++mf)
#pragma unroll
            for (int r = 0; r < 4; ++r) {
                int row = row0 + mf * 16 + lg * 4 + r;
                float v = fmaxf(acc[mf][nf][r] + bs, 0.f);
                if (OUT_F32) Cf[(size_t)row * N + col] = v;
                else         Ch[(size_t)row * N + col] = (half_t)v;
            }
    }
}

// ---------- final head: [NTOK,128] @ [128,3] + b ----------
__global__ __launch_bounds__(256) void head_kernel(
        const float* __restrict__ H, const float* __restrict__ W4,
        const float* __restrict__ b4, float* __restrict__ out) {
    __shared__ float Ws[128 * 3];
    __shared__ float bs[3];
    for (int i = threadIdx.x; i < 384; i += 256) Ws[i] = W4[i];
    if (threadIdx.x < 3) bs[threadIdx.x] = b4[threadIdx.x];
    __syncthreads();
    const int tok = blockIdx.x * 256 + threadIdx.x;
    const float* h = H + (size_t)tok * 128;
    float a0 = bs[0], a1 = bs[1], a2 = bs[2];
#pragma unroll
    for (int k = 0; k < 128; ++k) {
        float hv = h[k];
        a0 = fmaf(hv, Ws[k * 3 + 0], a0);
        a1 = fmaf(hv, Ws[k * 3 + 1], a1);
        a2 = fmaf(hv, Ws[k * 3 + 2], a2);
    }
    float* o = out + (size_t)tok * 3;
    o[0] = a0; o[1] = a1; o[2] = a2;
}

extern "C" void kernel_launch(void* const* d_in, const int* in_sizes, int n_in,
                              void* d_out, int out_size, void* d_ws, size_t ws_size,
                              hipStream_t stream) {
    (void)in_sizes; (void)n_in; (void)out_size; (void)ws_size;
    const float* x  = (const float*)d_in[0];
    const float* W1 = (const float*)d_in[1];
    const float* b1 = (const float*)d_in[2];
    const float* W2 = (const float*)d_in[3];
    const float* b2 = (const float*)d_in[4];
    const float* W3 = (const float*)d_in[5];
    const float* b3 = (const float*)d_in[6];
    const float* W4 = (const float*)d_in[7];
    const float* b4 = (const float*)d_in[8];
    float* out = (float*)d_out;

    // ws layout (bytes), total ~73.3 MB (well under the 146.5 MB known-safe)
    char* w = (char*)d_ws;
    half_t* H0    = (half_t*)(w);                                  // 64 MB
    half_t* H1    = (half_t*)(w + (size_t)64 * 1024 * 1024);       // 8 MB
    half_t* W1T   = (half_t*)(w + (size_t)72 * 1024 * 1024);       // 1 MB
    half_t* W2T   = (half_t*)(w + (size_t)73 * 1024 * 1024);       // 128 KB
    half_t* W3T   = W2T + 256 * 256;                               // 64 KB
    half_t* dftHi = W3T + 128 * 256;                               // 8 KB
    half_t* dftLo = dftHi + 64 * 64;                               // 8 KB
    // reuse H0 region once dead (after GEMM1):
    half_t* H2    = (half_t*)(w);                                  // 8 MB
    float*  H3    = (float*) (w + (size_t)8 * 1024 * 1024);        // 8 MB

    prep_kernel<<<2448, 256, 0, stream>>>(W1, W2, W3, dftHi, dftLo, W1T, W2T, W3T);
    fft_mfma_kernel<<<MROWS / 128, 256, 0, stream>>>(x, dftHi, dftLo, H0);

    // GEMM1: [16384,2048] x [2048,256]
    gemm_f16<256, false><<<dim3(NTOK / 64, 1), 256, 0, stream>>>(
        H0, KPAD, W1T, KPAD, b1, H1, nullptr, HID, KPAD);
    // GEMM2: [16384,256] x [256,256]
    gemm_f16<256, false><<<dim3(NTOK / 64, 1), 256, 0, stream>>>(
        H1, HID, W2T, HID, b2, H2, nullptr, HID, HID);
    // GEMM3: [16384,256] x [256,128] -> fp32
    gemm_f16<128, true><<<dim3(NTOK / 64, 1), 256, 0, stream>>>(
        H2, HID, W3T, HID, b3, nullptr, H3, HID / 2, HID);

    head_kernel<<<NTOK / 256, 256, 0, stream>>>(H3, W4, b4, out);
}

// Round 7
// 144.556 us; speedup vs baseline: 3.7774x; 1.1571x over previous
//
#include <hip/hip_runtime.h>
#include <math.h>

#define T_LEN 4096
#define NF 60
#define NBINS 33
#define TOTIN 2040   // 60 + 60*33
#define KPAD 2048
#define HID 256
#define NTOK 16384
#define MROWS (NTOK * NF)   // 983040
#define LINE 4160          // padded pre-reflected line length (mult of 8)

typedef _Float16 half_t;
typedef half_t half8 __attribute__((ext_vector_type(8)));
typedef float f32x4 __attribute__((ext_vector_type(4)));

// ---------- compile-time cos table: cos(2*pi*j/64), j=0..63 ----------
constexpr double K_PI = 3.14159265358979323846;
constexpr double tcos(double x) {
    while (x >  K_PI) x -= 2.0 * K_PI;
    while (x < -K_PI) x += 2.0 * K_PI;
    double x2 = x * x, s = 0.0, term = 1.0;
    for (int m = 0; m < 14; ++m) { s += term; term *= -x2 / ((2.0*m + 1.0) * (2.0*m + 2.0)); }
    return s;
}
struct CosTab { float v[64]; };
constexpr CosTab make_tab() {
    CosTab t{};
    for (int j = 0; j < 64; ++j) t.v[j] = (float)tcos(2.0 * K_PI * (double)j / 64.0);
    return t;
}
__device__ constexpr CosTab CTd = make_tab();

__device__ __forceinline__ float log1p_fast(float x) {
    return 0.69314718055994531f * __log2f(1.0f + x);
}

// ---------- one-time prep: fp16 DFT table + fp16 transposed weights ----------
// dft:  [64][64]  rows 0..32 = cos(2pi*r*n/64), rows 33..63 = sin rows
// W1T:  [256][2048] fp16, W1T[j][gk] = W1[perm(gk)][j], gk>=2040 -> 0
// W2T:  [256][256] fp16 transposed; W3T: [128][256] fp16 transposed
__global__ __launch_bounds__(256) void prep_kernel(
        const float* __restrict__ W1, const float* __restrict__ W2,
        const float* __restrict__ W3,
        half_t* __restrict__ dftH,
        half_t* __restrict__ W1T, half_t* __restrict__ W2T,
        half_t* __restrict__ W3T) {
    int i = blockIdx.x * 256 + threadIdx.x;
    if (i < 4096) {
        int row = i >> 6, n = i & 63;
        float c = (row < 33) ? CTd.v[(row * n) & 63]
                             : CTd.v[((row - 32) * n + 48) & 63];
        dftH[i] = (half_t)c;
        return;
    }
    i -= 4096;
    if (i < 256 * KPAD) {
        int gk = i & (KPAD - 1);
        float v = 0.f;
        if (gk < TOTIN) {
            int j = i >> 11;
            int r = gk;
            if (gk >= NF) { int q = gk - NF; r = NF + (q % NF) * NBINS + (q / NF); }
            v = W1[(size_t)r * HID + j];
        }
        W1T[i] = (half_t)v;
        return;
    }
    i -= 256 * KPAD;
    if (i < 256 * 256) {
        int k = i & 255, j = i >> 8;
        W2T[i] = (half_t)W2[(size_t)k * HID + j];
        return;
    }
    i -= 256 * 256;
    if (i < 128 * 256) {
        int k = i & 255, j = i >> 8;
        W3T[i] = (half_t)W3[(size_t)k * 128 + j];
    }
}

// ---------- pre-reflected, phase-shifted fp16 copies of x ----------
// xTc[(b*60+f)*8 + c][j] = (fp16) x[b][reflect(j + c - 32)][f], j in [0,LINE).
// Window (t,f) chunk at offset n (mult of 8) = 8 contiguous halfs at
// 16B-aligned addr in copy c = t&7, index t - c + n.
__global__ __launch_bounds__(256) void xcopy_kernel(
        const float* __restrict__ x, half_t* __restrict__ xTc) {
    const int bf = blockIdx.x;             // 0..239 = b*60+f
    const int b = bf / NF, f = bf - b * NF;
    const float* xb = x + (size_t)b * T_LEN * NF + f;
    half_t* base = xTc + (size_t)bf * 8 * LINE;
    for (int j = threadIdx.x; j <= 4158; j += 256) {
        int s = j - 32;
        int r = (s < 0) ? -s : ((s > T_LEN - 1) ? 2 * (T_LEN - 1) - s : s);
        half_t v = (half_t)xb[(size_t)r * NF];
#pragma unroll
        for (int c = 0; c < 8; ++c) {
            int jp = j - c;
            if (jp >= 0) base[c * LINE + jp] = v;
        }
    }
}

// ---------- MFMA sliding-window DFT: register-direct B, no LDS ----------
// D[bin_row, m] = sum_n DFT[row][n]*win[m][n], m = tok*60+f.
// B-frags loaded directly from phase-aligned global copies.
__global__ __launch_bounds__(256) void fft_mfma_kernel(
        const half_t* __restrict__ xTc, const half_t* __restrict__ dftH,
        half_t* __restrict__ H0) {
    const int tid  = threadIdx.x;
    const int m0   = blockIdx.x * 128;
    const int lane = tid & 63, wv = tid >> 6;
    const int lr   = lane & 15, lg = lane >> 4;

    // A fragments (8 KB table, L2-resident)
    half8 a[4][2];
#pragma unroll
    for (int rf = 0; rf < 4; ++rf)
#pragma unroll
        for (int ks = 0; ks < 2; ++ks)
            a[rf][ks] = *(const half8*)&dftH[(16 * rf + lr) * 64 + ks * 32 + lg * 8];

    f32x4 acc[4][2] = {};
#pragma unroll
    for (int cf = 0; cf < 2; ++cf) {
        const int gm = m0 + wv * 32 + cf * 16 + lr;
        const int tok = gm / NF, f = gm - tok * NF;
        const int b = tok >> 12, t = tok & (T_LEN - 1);
        const int c = t & 7;
        const half_t* base = xTc + ((size_t)((b * NF + f) * 8 + c)) * LINE + (t - c);

        // raw-feature passthrough (sample n=32 == x[t][f]) + K-pad zero
        H0[(size_t)tok * KPAD + f] = base[32];
        if (f == 0) {
            half8 z = {};
            *(half8*)&H0[(size_t)tok * KPAD + TOTIN] = z;
        }

        half8 bfrag[2];
        bfrag[0] = *(const half8*)(base + lg * 8);          // ks=0, 16B-aligned
        bfrag[1] = *(const half8*)(base + 32 + lg * 8);     // ks=1
#pragma unroll
        for (int ks = 0; ks < 2; ++ks)
#pragma unroll
            for (int rf = 0; rf < 4; ++rf)
                acc[rf][cf] = __builtin_amdgcn_mfma_f32_16x16x32_f16(a[rf][ks], bfrag[ks], acc[rf][cf], 0, 0, 0);
    }

    // epilogue: mag -> log1p -> fp16 bin-major store
    // C/D map: col = lane&15 (m), row-in-frag = lg*4 + r.
    // re_k in frag k/16 (k=0..31); im_k (row 32+k) in frags 2,3 same lane/reg.
    // frag2 reg0 lg=0 holds re_32.
#pragma unroll
    for (int cf = 0; cf < 2; ++cf) {
        const int gm = m0 + wv * 32 + cf * 16 + lr;
        const int tok = gm / NF, f = gm - tok * NF;
        half_t* ob = H0 + (size_t)tok * KPAD + 60 + f;
#pragma unroll
        for (int rf = 0; rf < 2; ++rf)
#pragma unroll
            for (int r = 0; r < 4; ++r) {
                const int k = 16 * rf + lg * 4 + r;
                float re = acc[rf][cf][r];
                float im = acc[rf + 2][cf][r];
                if (rf == 0 && r == 0 && lg == 0) {
                    ob[0]       = (half_t)log1p_fast(fabsf(re));   // bin 0
                    ob[32 * 60] = (half_t)log1p_fast(fabsf(im));   // bin 32 (re_32)
                } else {
                    ob[k * 60] = (half_t)log1p_fast(sqrtf(re * re + im * im));
                }
            }
    }
}

// ---------- fp16 single-product MFMA GEMM ----------
// C[M,N] = relu(A[M,K] @ BT^T + bias). BM=64, BN=N (A read once, B L2-resident).
template<int BN, bool OUT_F32>
__global__ __launch_bounds__(256, 2) void gemm_f16(
        const half_t* __restrict__ A, int lda,
        const half_t* __restrict__ BT, int ldb,
        const float* __restrict__ bias,
        half_t* __restrict__ Ch, float* __restrict__ Cf,
        int N, int K) {
    constexpr int BM = 64;
    constexpr int NFR = BN / 64;          // n-frags per wave: 4 or 2
    constexpr int BUNITS = BN * 8 / 256;  // half8 B-units per thread
    __shared__ half_t As[BM][72];
    __shared__ half_t Bs[BN][72];

    const int tid  = threadIdx.x;
    const int row0 = blockIdx.x * BM;
    const int wv = tid >> 6, lane = tid & 63;
    const int lr = lane & 15, lg = lane >> 4;

    const int arow = tid >> 2, ak = (tid & 3) * 16;
    const half_t* ap = A + (size_t)(row0 + arow) * lda + ak;

    f32x4 acc[4][NFR] = {};

    for (int k0 = 0; k0 < K; k0 += 64) {
        half8 av0 = *(const half8*)(ap + k0);
        half8 av1 = *(const half8*)(ap + k0 + 8);
        half8 bv[BUNITS];
#pragma unroll
        for (int u = 0; u < BUNITS; ++u) {
            int e = tid + u * 256;
            int n = e >> 3, c8 = (e & 7) * 8;
            bv[u] = *(const half8*)(BT + (size_t)n * ldb + k0 + c8);
        }

        __syncthreads();   // previous iter's frag reads done

        *(half8*)&As[arow][ak]     = av0;
        *(half8*)&As[arow][ak + 8] = av1;
#pragma unroll
        for (int u = 0; u < BUNITS; ++u) {
            int e = tid + u * 256;
            int n = e >> 3, c8 = (e & 7) * 8;
            *(half8*)&Bs[n][c8] = bv[u];
        }

        __syncthreads();   // tile staged

#pragma unroll
        for (int ks = 0; ks < 2; ++ks) {
            half8 af[4], bf[NFR];
#pragma unroll
            for (int mf = 0; mf < 4; ++mf)
                af[mf] = *(const half8*)&As[mf * 16 + lr][ks * 32 + lg * 8];
#pragma unroll
            for (int nf = 0; nf < NFR; ++nf)
                bf[nf] = *(const half8*)&Bs[wv * (16 * NFR) + nf * 16 + lr][ks * 32 + lg * 8];
#pragma unroll
            for (int mf = 0; mf < 4; ++mf)
#pragma unroll
                for (int nf = 0; nf < NFR; ++nf)
                    acc[mf][nf] = __builtin_amdgcn_mfma_f32_16x16x32_f16(af[mf], bf[nf], acc[mf][nf], 0, 0, 0);
        }
    }

    // epilogue: bias + relu; C/D map col=lane&15, row=(lane>>4)*4+reg
#pragma unroll
    for (int nf = 0; nf < NFR; ++nf) {
        int col = wv * (16 * NFR) + nf * 16 + lr;
        float bs = bias[col];
#pragma unroll
        for (int mf = 0; mf < 4; ++mf)
#pragma unroll
            for (int r = 0; r < 4; ++r) {
                int row = row0 + mf * 16 + lg * 4 + r;
                float v = fmaxf(acc[mf][nf][r] + bs, 0.f);
                if (OUT_F32) Cf[(size_t)row * N + col] = v;
                else         Ch[(size_t)row * N + col] = (half_t)v;
            }
    }
}

// ---------- final head: [NTOK,128] @ [128,3] + b ----------
__global__ __launch_bounds__(256) void head_kernel(
        const float* __restrict__ H, const float* __restrict__ W4,
        const float* __restrict__ b4, float* __restrict__ out) {
    __shared__ float Ws[128 * 3];
    __shared__ float bs[3];
    for (int i = threadIdx.x; i < 384; i += 256) Ws[i] = W4[i];
    if (threadIdx.x < 3) bs[threadIdx.x] = b4[threadIdx.x];
    __syncthreads();
    const int tok = blockIdx.x * 256 + threadIdx.x;
    const float* h = H + (size_t)tok * 128;
    float a0 = bs[0], a1 = bs[1], a2 = bs[2];
#pragma unroll
    for (int k = 0; k < 128; ++k) {
        float hv = h[k];
        a0 = fmaf(hv, Ws[k * 3 + 0], a0);
        a1 = fmaf(hv, Ws[k * 3 + 1], a1);
        a2 = fmaf(hv, Ws[k * 3 + 2], a2);
    }
    float* o = out + (size_t)tok * 3;
    o[0] = a0; o[1] = a1; o[2] = a2;
}

extern "C" void kernel_launch(void* const* d_in, const int* in_sizes, int n_in,
                              void* d_out, int out_size, void* d_ws, size_t ws_size,
                              hipStream_t stream) {
    (void)in_sizes; (void)n_in; (void)out_size; (void)ws_size;
    const float* x  = (const float*)d_in[0];
    const float* W1 = (const float*)d_in[1];
    const float* b1 = (const float*)d_in[2];
    const float* W2 = (const float*)d_in[3];
    const float* b2 = (const float*)d_in[4];
    const float* W3 = (const float*)d_in[5];
    const float* b3 = (const float*)d_in[6];
    const float* W4 = (const float*)d_in[7];
    const float* b4 = (const float*)d_in[8];
    float* out = (float*)d_out;

    // ws layout (bytes), total ~106 MB (< 146.5 MB known-safe)
    char* w = (char*)d_ws;
    half_t* H0    = (half_t*)(w);                                  // 64 MB
    half_t* H1    = (half_t*)(w + (size_t)64 * 1024 * 1024);       // 8 MB
    half_t* W1T   = (half_t*)(w + (size_t)72 * 1024 * 1024);       // 1 MB
    half_t* W2T   = (half_t*)(w + (size_t)73 * 1024 * 1024);       // 128 KB
    half_t* W3T   = W2T + 256 * 256;                               // 64 KB
    half_t* dftH  = W3T + 128 * 256;                               // 8 KB
    half_t* xTc   = (half_t*)(w + (size_t)74 * 1024 * 1024);       // 31.7 MB
    // reuse H0 region once dead (after GEMM1):
    half_t* H2    = (half_t*)(w);                                  // 8 MB
    float*  H3    = (float*) (w + (size_t)8 * 1024 * 1024);        // 8 MB

    prep_kernel<<<2448, 256, 0, stream>>>(W1, W2, W3, dftH, W1T, W2T, W3T);
    xcopy_kernel<<<240, 256, 0, stream>>>(x, xTc);
    fft_mfma_kernel<<<MROWS / 128, 256, 0, stream>>>(xTc, dftH, H0);

    // GEMM1: [16384,2048] x [2048,256]
    gemm_f16<256, false><<<dim3(NTOK / 64, 1), 256, 0, stream>>>(
        H0, KPAD, W1T, KPAD, b1, H1, nullptr, HID, KPAD);
    // GEMM2: [16384,256] x [256,256]
    gemm_f16<256, false><<<dim3(NTOK / 64, 1), 256, 0, stream>>>(
        H1, HID, W2T, HID, b2, H2, nullptr, HID, HID);
    // GEMM3: [16384,256] x [256,128] -> fp32
    gemm_f16<128, true><<<dim3(NTOK / 64, 1), 256, 0, stream>>>(
        H2, HID, W3T, HID, b3, nullptr, H3, HID / 2, HID);

    head_kernel<<<NTOK / 256, 256, 0, stream>>>(H3, W4, b4, out);
}

// Round 8
// 138.342 us; speedup vs baseline: 3.9471x; 1.0449x over previous
//
#include <hip/hip_runtime.h>
#include <math.h>

#define T_LEN 4096
#define NF 60
#define NBINS 33
#define TOTIN 2040   // 60 + 60*33
#define KPAD 2048
#define HID 256
#define NTOK 16384
#define MROWS (NTOK * NF)   // 983040
#define LINE 4160          // padded pre-reflected line length (mult of 8)

typedef _Float16 half_t;
typedef half_t half8 __attribute__((ext_vector_type(8)));
typedef half_t half4 __attribute__((ext_vector_type(4)));
typedef float f32x4 __attribute__((ext_vector_type(4)));

// ---------- compile-time cos table: cos(2*pi*j/64), j=0..63 ----------
constexpr double K_PI = 3.14159265358979323846;
constexpr double tcos(double x) {
    while (x >  K_PI) x -= 2.0 * K_PI;
    while (x < -K_PI) x += 2.0 * K_PI;
    double x2 = x * x, s = 0.0, term = 1.0;
    for (int m = 0; m < 14; ++m) { s += term; term *= -x2 / ((2.0*m + 1.0) * (2.0*m + 2.0)); }
    return s;
}
struct CosTab { float v[64]; };
constexpr CosTab make_tab() {
    CosTab t{};
    for (int j = 0; j < 64; ++j) t.v[j] = (float)tcos(2.0 * K_PI * (double)j / 64.0);
    return t;
}
__device__ constexpr CosTab CTd = make_tab();

__device__ __forceinline__ float log1p_fast(float x) {
    return 0.69314718055994531f * __log2f(1.0f + x);
}

// ---------- one-time prep: fp16 DFT table + fp16 transposed weights ----------
// H0 k-layout: [0..59]=raw x; [60+f*32+j]=bin j+? NO: bins 0..31 at 60+f*32+bin;
// [1980+f]=bin 32; [2040..2047]=0.  W1T maps back to reference rows
// (ref col = 60 + f*33 + bin).
__global__ __launch_bounds__(256) void prep_kernel(
        const float* __restrict__ W1, const float* __restrict__ W2,
        const float* __restrict__ W3,
        half_t* __restrict__ dftH,
        half_t* __restrict__ W1T, half_t* __restrict__ W2T,
        half_t* __restrict__ W3T) {
    int i = blockIdx.x * 256 + threadIdx.x;
    if (i < 4096) {
        int row = i >> 6, n = i & 63;
        float c = (row < 33) ? CTd.v[(row * n) & 63]
                             : CTd.v[((row - 32) * n + 48) & 63];
        dftH[i] = (half_t)c;
        return;
    }
    i -= 4096;
    if (i < 256 * KPAD) {
        int gk = i & (KPAD - 1);
        float v = 0.f;
        if (gk < TOTIN) {
            int j = i >> 11;
            int r;
            if (gk < NF) {
                r = gk;                                   // raw feature
            } else if (gk < 1980) {
                int q = gk - NF, f = q >> 5, bin = q & 31;
                r = NF + f * NBINS + bin;                 // bins 0..31
            } else {
                int f = gk - 1980;
                r = NF + f * NBINS + 32;                  // bin 32
            }
            v = W1[(size_t)r * HID + j];
        }
        W1T[i] = (half_t)v;
        return;
    }
    i -= 256 * KPAD;
    if (i < 256 * 256) {
        int k = i & 255, j = i >> 8;
        W2T[i] = (half_t)W2[(size_t)k * HID + j];
        return;
    }
    i -= 256 * 256;
    if (i < 128 * 256) {
        int k = i & 255, j = i >> 8;
        W3T[i] = (half_t)W3[(size_t)k * 128 + j];
    }
}

// ---------- pre-reflected, phase-shifted fp16 copies of x (LDS-staged) ------
// xTc[(b*60+f)*8 + c][jp] = (fp16) x[b][reflect(jp + c - 32)][f].
// Stage the reflected line once in LDS, then 8 coalesced half8-store sweeps.
__global__ __launch_bounds__(256) void xcopy_kernel(
        const float* __restrict__ x, half_t* __restrict__ xTc) {
    __shared__ half_t line[LINE + 8];
    const int bf = blockIdx.x;             // 0..239 = b*60+f
    const int b = bf / NF, f = bf - b * NF;
    const float* xb = x + (size_t)b * T_LEN * NF + f;
    for (int j = threadIdx.x; j < LINE + 8; j += 256) {
        int s = j - 32;
        int r = (s < 0) ? -s : ((s > T_LEN - 1) ? 2 * (T_LEN - 1) - s : s);
        line[j] = (half_t)xb[(size_t)r * NF];
    }
    __syncthreads();
    half_t* base = xTc + (size_t)bf * 8 * LINE;
#pragma unroll
    for (int c = 0; c < 8; ++c) {
        for (int j8 = threadIdx.x * 8; j8 < LINE; j8 += 2048) {
            half8 v;
#pragma unroll
            for (int i = 0; i < 8; ++i) v[i] = line[j8 + c + i];
            *(half8*)&base[c * LINE + j8] = v;
        }
    }
}

// ---------- MFMA sliding-window DFT: register-direct B, no LDS ----------
// D[bin_row, m] = sum_n DFT[row][n]*win[m][n], m = tok*60+f.
__global__ __launch_bounds__(256) void fft_mfma_kernel(
        const half_t* __restrict__ xTc, const half_t* __restrict__ dftH,
        half_t* __restrict__ H0) {
    const int tid  = threadIdx.x;
    const int m0   = blockIdx.x * 128;
    const int lane = tid & 63, wv = tid >> 6;
    const int lr   = lane & 15, lg = lane >> 4;

    // A fragments (8 KB table, L2-resident)
    half8 a[4][2];
#pragma unroll
    for (int rf = 0; rf < 4; ++rf)
#pragma unroll
        for (int ks = 0; ks < 2; ++ks)
            a[rf][ks] = *(const half8*)&dftH[(16 * rf + lr) * 64 + ks * 32 + lg * 8];

    f32x4 acc[4][2] = {};
#pragma unroll
    for (int cf = 0; cf < 2; ++cf) {
        const int gm = m0 + wv * 32 + cf * 16 + lr;
        const int tok = gm / NF, f = gm - tok * NF;
        const int b = tok >> 12, t = tok & (T_LEN - 1);
        const int c = t & 7;
        const half_t* base = xTc + ((size_t)((b * NF + f) * 8 + c)) * LINE + (t - c);

        // raw-feature passthrough (sample n=32 == x[t][f]) + K-pad zero
        H0[(size_t)tok * KPAD + f] = base[32];
        if (f == 0) {
            half8 z = {};
            *(half8*)&H0[(size_t)tok * KPAD + TOTIN] = z;
        }

        half8 bfrag[2];
        bfrag[0] = *(const half8*)(base + lg * 8);          // ks=0, 16B-aligned
        bfrag[1] = *(const half8*)(base + 32 + lg * 8);     // ks=1
#pragma unroll
        for (int ks = 0; ks < 2; ++ks)
#pragma unroll
            for (int rf = 0; rf < 4; ++rf)
                acc[rf][cf] = __builtin_amdgcn_mfma_f32_16x16x32_f16(a[rf][ks], bfrag[ks], acc[rf][cf], 0, 0, 0);
    }

    // epilogue: mag -> log1p -> VECTOR half4 stores, grouped-bin layout.
    // C/D map: col = lane&15 (m), row-in-frag = lg*4 + r.
    // re of bin k in frag k/16 (rows 0..31); im rows 32.. in frags 2,3.
    // frag2 reg0 lg=0 holds re_32 (row 32).  Bin k (0..31) -> H0 col 60+f*32+k;
    // bin 32 -> col 1980+f.
#pragma unroll
    for (int cf = 0; cf < 2; ++cf) {
        const int gm = m0 + wv * 32 + cf * 16 + lr;
        const int tok = gm / NF, f = gm - tok * NF;
        half_t* base = H0 + (size_t)tok * KPAD;
#pragma unroll
        for (int rf = 0; rf < 2; ++rf) {
            half4 h4;
#pragma unroll
            for (int r = 0; r < 4; ++r) {
                float re = acc[rf][cf][r];
                float im = acc[rf + 2][cf][r];
                float v;
                if (rf == 0 && r == 0) {
                    // lg==0 here is bin 0 (im slot holds re_32, not im_0)
                    v = (lg == 0) ? log1p_fast(fabsf(re))
                                  : log1p_fast(sqrtf(re * re + im * im));
                } else {
                    v = log1p_fast(sqrtf(re * re + im * im));
                }
                h4[r] = (half_t)v;
            }
            *(half4*)&base[60 + f * 32 + 16 * rf + 4 * lg] = h4;
        }
        if (lg == 0) {   // bin 32 = |re_32| from im-slot frag2 reg0
            base[1980 + f] = (half_t)log1p_fast(fabsf(acc[2][cf][0]));
        }
    }
}

// ---------- fp16 single-product MFMA GEMM ----------
// C[M,N] = relu(A[M,K] @ BT^T + bias). BM=64, BN=N (A read once, B L2-resident).
template<int BN, bool OUT_F32>
__global__ __launch_bounds__(256, 2) void gemm_f16(
        const half_t* __restrict__ A, int lda,
        const half_t* __restrict__ BT, int ldb,
        const float* __restrict__ bias,
        half_t* __restrict__ Ch, float* __restrict__ Cf,
        int N, int K) {
    constexpr int BM = 64;
    constexpr int NFR = BN / 64;          // n-frags per wave: 4 or 2
    constexpr int BUNITS = BN * 8 / 256;  // half8 B-units per thread
    __shared__ half_t As[BM][72];
    __shared__ half_t Bs[BN][72];

    const int tid  = threadIdx.x;
    const int row0 = blockIdx.x * BM;
    const int wv = tid >> 6, lane = tid & 63;
    const int lr = lane & 15, lg = lane >> 4;

    const int arow = tid >> 2, ak = (tid & 3) * 16;
    const half_t* ap = A + (size_t)(row0 + arow) * lda + ak;

    f32x4 acc[4][NFR] = {};

    for (int k0 = 0; k0 < K; k0 += 64) {
        half8 av0 = *(const half8*)(ap + k0);
        half8 av1 = *(const half8*)(ap + k0 + 8);
        half8 bv[BUNITS];
#pragma unroll
        for (int u = 0; u < BUNITS; ++u) {
            int e = tid + u * 256;
            int n = e >> 3, c8 = (e & 7) * 8;
            bv[u] = *(const half8*)(BT + (size_t)n * ldb + k0 + c8);
        }

        __syncthreads();   // previous iter's frag reads done

        *(half8*)&As[arow][ak]     = av0;
        *(half8*)&As[arow][ak + 8] = av1;
#pragma unroll
        for (int u = 0; u < BUNITS; ++u) {
            int e = tid + u * 256;
            int n = e >> 3, c8 = (e & 7) * 8;
            *(half8*)&Bs[n][c8] = bv[u];
        }

        __syncthreads();   // tile staged

#pragma unroll
        for (int ks = 0; ks < 2; ++ks) {
            half8 af[4], bf[NFR];
#pragma unroll
            for (int mf = 0; mf < 4; ++mf)
                af[mf] = *(const half8*)&As[mf * 16 + lr][ks * 32 + lg * 8];
#pragma unroll
            for (int nf = 0; nf < NFR; ++nf)
                bf[nf] = *(const half8*)&Bs[wv * (16 * NFR) + nf * 16 + lr][ks * 32 + lg * 8];
#pragma unroll
            for (int mf = 0; mf < 4; ++mf)
#pragma unroll
                for (int nf = 0; nf < NFR; ++nf)
                    acc[mf][nf] = __builtin_amdgcn_mfma_f32_16x16x32_f16(af[mf], bf[nf], acc[mf][nf], 0, 0, 0);
        }
    }

    // epilogue: bias + relu; C/D map col=lane&15, row=(lane>>4)*4+reg
#pragma unroll
    for (int nf = 0; nf < NFR; ++nf) {
        int col = wv * (16 * NFR) + nf * 16 + lr;
        float bs = bias[col];
#pragma unroll
        for (int mf = 0; mf < 4; ++mf)
#pragma unroll
            for (int r = 0; r < 4; ++r) {
                int row = row0 + mf * 16 + lg * 4 + r;
                float v = fmaxf(acc[mf][nf][r] + bs, 0.f);
                if (OUT_F32) Cf[(size_t)row * N + col] = v;
                else         Ch[(size_t)row * N + col] = (half_t)v;
            }
    }
}

// ---------- final head: [NTOK,128] @ [128,3] + b ----------
__global__ __launch_bounds__(256) void head_kernel(
        const float* __restrict__ H, const float* __restrict__ W4,
        const float* __restrict__ b4, float* __restrict__ out) {
    __shared__ float Ws[128 * 3];
    __shared__ float bs[3];
    for (int i = threadIdx.x; i < 384; i += 256) Ws[i] = W4[i];
    if (threadIdx.x < 3) bs[threadIdx.x] = b4[threadIdx.x];
    __syncthreads();
    const int tok = blockIdx.x * 256 + threadIdx.x;
    const float* h = H + (size_t)tok * 128;
    float a0 = bs[0], a1 = bs[1], a2 = bs[2];
#pragma unroll
    for (int k = 0; k < 128; ++k) {
        float hv = h[k];
        a0 = fmaf(hv, Ws[k * 3 + 0], a0);
        a1 = fmaf(hv, Ws[k * 3 + 1], a1);
        a2 = fmaf(hv, Ws[k * 3 + 2], a2);
    }
    float* o = out + (size_t)tok * 3;
    o[0] = a0; o[1] = a1; o[2] = a2;
}

extern "C" void kernel_launch(void* const* d_in, const int* in_sizes, int n_in,
                              void* d_out, int out_size, void* d_ws, size_t ws_size,
                              hipStream_t stream) {
    (void)in_sizes; (void)n_in; (void)out_size; (void)ws_size;
    const float* x  = (const float*)d_in[0];
    const float* W1 = (const float*)d_in[1];
    const float* b1 = (const float*)d_in[2];
    const float* W2 = (const float*)d_in[3];
    const float* b2 = (const float*)d_in[4];
    const float* W3 = (const float*)d_in[5];
    const float* b3 = (const float*)d_in[6];
    const float* W4 = (const float*)d_in[7];
    const float* b4 = (const float*)d_in[8];
    float* out = (float*)d_out;

    // ws layout (bytes), total ~106 MB (< 146.5 MB known-safe)
    char* w = (char*)d_ws;
    half_t* H0    = (half_t*)(w);                                  // 64 MB
    half_t* H1    = (half_t*)(w + (size_t)64 * 1024 * 1024);       // 8 MB
    half_t* W1T   = (half_t*)(w + (size_t)72 * 1024 * 1024);       // 1 MB
    half_t* W2T   = (half_t*)(w + (size_t)73 * 1024 * 1024);       // 128 KB
    half_t* W3T   = W2T + 256 * 256;                               // 64 KB
    half_t* dftH  = W3T + 128 * 256;                               // 8 KB
    half_t* xTc   = (half_t*)(w + (size_t)74 * 1024 * 1024);       // 31.7 MB
    // reuse H0 region once dead (after GEMM1):
    half_t* H2    = (half_t*)(w);                                  // 8 MB
    float*  H3    = (float*) (w + (size_t)8 * 1024 * 1024);        // 8 MB

    prep_kernel<<<2448, 256, 0, stream>>>(W1, W2, W3, dftH, W1T, W2T, W3T);
    xcopy_kernel<<<240, 256, 0, stream>>>(x, xTc);
    fft_mfma_kernel<<<MROWS / 128, 256, 0, stream>>>(xTc, dftH, H0);

    // GEMM1: [16384,2048] x [2048,256]
    gemm_f16<256, false><<<dim3(NTOK / 64, 1), 256, 0, stream>>>(
        H0, KPAD, W1T, KPAD, b1, H1, nullptr, HID, KPAD);
    // GEMM2: [16384,256] x [256,256]
    gemm_f16<256, false><<<dim3(NTOK / 64, 1), 256, 0, stream>>>(
        H1, HID, W2T, HID, b2, H2, nullptr, HID, HID);
    // GEMM3: [16384,256] x [256,128] -> fp32
    gemm_f16<128, true><<<dim3(NTOK / 64, 1), 256, 0, stream>>>(
        H2, HID, W3T, HID, b3, nullptr, H3, HID / 2, HID);

    head_kernel<<<NTOK / 256, 256, 0, stream>>>(H3, W4, b4, out);
}

// Round 9
// 137.043 us; speedup vs baseline: 3.9845x; 1.0095x over previous
//
#include <hip/hip_runtime.h>
#include <math.h>

#define T_LEN 4096
#define NF 60
#define NBINS 33
#define TOTIN 2040   // 60 + 60*33
#define KPAD 2048
#define HID 256
#define NTOK 16384
#define LINE 4160    // padded pre-reflected line length (mult of 8)

typedef _Float16 half_t;
typedef half_t half8 __attribute__((ext_vector_type(8)));
typedef half_t half4 __attribute__((ext_vector_type(4)));
typedef float f32x4 __attribute__((ext_vector_type(4)));

// ---------- compile-time cos table: cos(2*pi*j/64), j=0..63 ----------
constexpr double K_PI = 3.14159265358979323846;
constexpr double tcos(double x) {
    while (x >  K_PI) x -= 2.0 * K_PI;
    while (x < -K_PI) x += 2.0 * K_PI;
    double x2 = x * x, s = 0.0, term = 1.0;
    for (int m = 0; m < 14; ++m) { s += term; term *= -x2 / ((2.0*m + 1.0) * (2.0*m + 2.0)); }
    return s;
}
struct CosTab { float v[64]; };
constexpr CosTab make_tab() {
    CosTab t{};
    for (int j = 0; j < 64; ++j) t.v[j] = (float)tcos(2.0 * K_PI * (double)j / 64.0);
    return t;
}
__device__ constexpr CosTab CTd = make_tab();

__device__ __forceinline__ float log1p_fast(float x) {
    return 0.69314718055994531f * __log2f(1.0f + x);
}

// ---------- one-time prep: fp16 DFT table + fp16 transposed weights ----------
// NEW fused k-layout: k in [0,1920) = bins: f = k>>5, bin = k&31;
// [1920,1980) = raw feature k-1920; [1980,2040) = bin32 of f = k-1980;
// [2040,2048) = zero.  W1T[j][k] maps back to reference row accordingly.
__global__ __launch_bounds__(256) void prep_kernel(
        const float* __restrict__ W1, const float* __restrict__ W2,
        const float* __restrict__ W3,
        half_t* __restrict__ dftH,
        half_t* __restrict__ W1T, half_t* __restrict__ W2T,
        half_t* __restrict__ W3T) {
    int i = blockIdx.x * 256 + threadIdx.x;
    if (i < 4096) {
        int row = i >> 6, n = i & 63;
        float c = (row < 33) ? CTd.v[(row * n) & 63]
                             : CTd.v[((row - 32) * n + 48) & 63];
        dftH[i] = (half_t)c;
        return;
    }
    i -= 4096;
    if (i < 256 * KPAD) {
        int gk = i & (KPAD - 1);
        float v = 0.f;
        if (gk < 2040) {
            int j = i >> 11;
            int r;
            if (gk < 1920) {
                int f = gk >> 5, bin = gk & 31;
                r = NF + f * NBINS + bin;                 // bins 0..31
            } else if (gk < 1980) {
                r = gk - 1920;                            // raw feature
            } else {
                r = NF + (gk - 1980) * NBINS + 32;        // bin 32
            }
            v = W1[(size_t)r * HID + j];
        }
        W1T[i] = (half_t)v;
        return;
    }
    i -= 256 * KPAD;
    if (i < 256 * 256) {
        int k = i & 255, j = i >> 8;
        W2T[i] = (half_t)W2[(size_t)k * HID + j];
        return;
    }
    i -= 256 * 256;
    if (i < 128 * 256) {
        int k = i & 255, j = i >> 8;
        W3T[i] = (half_t)W3[(size_t)k * 128 + j];
    }
}

// ---------- pre-reflected, phase-shifted fp16 copies of x (LDS-staged) ------
__global__ __launch_bounds__(256) void xcopy_kernel(
        const float* __restrict__ x, half_t* __restrict__ xTc) {
    __shared__ half_t line[LINE + 8];
    const int bf = blockIdx.x;             // 0..239 = b*60+f
    const int b = bf / NF, f = bf - b * NF;
    const float* xb = x + (size_t)b * T_LEN * NF + f;
    for (int j = threadIdx.x; j < LINE + 8; j += 256) {
        int s = j - 32;
        int r = (s < 0) ? -s : ((s > T_LEN - 1) ? 2 * (T_LEN - 1) - s : s);
        line[j] = (half_t)xb[(size_t)r * NF];
    }
    __syncthreads();
    half_t* base = xTc + (size_t)bf * 8 * LINE;
#pragma unroll
    for (int c = 0; c < 8; ++c) {
        for (int j8 = threadIdx.x * 8; j8 < LINE; j8 += 2048) {
            half8 v;
#pragma unroll
            for (int i = 0; i < 8; ++i) v[i] = line[j8 + c + i];
            *(half8*)&base[c * LINE + j8] = v;
        }
    }
}

// ---------- FUSED: sliding-window DFT (MFMA) + GEMM1, feat in LDS ----------
// Block = 32 tokens. Loop c=0..29: DFT f-pair {2c,2c+1} -> Af[32][64] feats
// -> GEMM1 k-chunk (A from LDS, B=W1T from L2). Raw + bin32 collect in Sd,
// consumed as chunks 30,31. Output H1 = relu(feat @ W1 + b1) fp16.
__global__ __launch_bounds__(256, 2) void fused_fft_gemm1(
        const half_t* __restrict__ xTc, const half_t* __restrict__ dftH,
        const float* __restrict__ x, const half_t* __restrict__ W1T,
        const float* __restrict__ bias, half_t* __restrict__ H1) {
    __shared__ half_t Af[32][72];    // feat tile: 32 tok x 64 k (+pad)
    __shared__ half_t Sd[32][136];   // side: raw 0..59, bin32 60..119, 0-pad 120..127

    const int tid  = threadIdx.x;
    const int tok0 = blockIdx.x * 32;
    const int bb   = tok0 >> 12;
    const int t0   = tok0 & (T_LEN - 1);
    const int lane = tid & 63, wv = tid >> 6;
    const int lr   = lane & 15, lg = lane >> 4;

    // DFT A-fragments (8 KB table, L2-resident)
    half8 a[4][2];
#pragma unroll
    for (int rf = 0; rf < 4; ++rf)
#pragma unroll
        for (int ks = 0; ks < 2; ++ks)
            a[rf][ks] = *(const half8*)&dftH[(16 * rf + lr) * 64 + ks * 32 + lg * 8];

    // side buffer: raw features (exact fp16(x)) + zero pad
    for (int i = tid; i < 32 * NF; i += 256) {
        int tl = i / NF, f = i - tl * NF;
        Sd[tl][f] = (half_t)x[(size_t)(tok0 + tl) * NF + f];
    }
    if (tid < 32) { half8 z = {}; *(half8*)&Sd[tid][120] = z; }

    // this thread's window identity (fixed across chunks)
    const int mm = wv * 16 + lr;        // 0..63 = fl*32 + tl
    const int fl = mm >> 5, tl = mm & 31;
    const int t  = t0 + tl;
    const int ph = t & 7;

    f32x4 gacc[2][4] = {};              // [mf][nf]

    for (int c = 0; c < 32; ++c) {
        f32x4 dacc[4] = {};
        int f = 0;
        if (c < 30) {
            f = 2 * c + fl;
            const half_t* base = xTc + ((size_t)((bb * NF + f) * 8 + ph)) * LINE + (t - ph);
            half8 w0 = *(const half8*)(base + lg * 8);
            half8 w1 = *(const half8*)(base + 32 + lg * 8);
#pragma unroll
            for (int rf = 0; rf < 4; ++rf)
                dacc[rf] = __builtin_amdgcn_mfma_f32_16x16x32_f16(a[rf][0], w0, dacc[rf], 0, 0, 0);
#pragma unroll
            for (int rf = 0; rf < 4; ++rf)
                dacc[rf] = __builtin_amdgcn_mfma_f32_16x16x32_f16(a[rf][1], w1, dacc[rf], 0, 0, 0);
        }
        __syncthreads();   // previous chunk's Af reads complete
        if (c < 30) {
            // D rows: rf0=re0..15, rf1=re16..31, rf2=row32(re32)+im1..15, rf3=im16..31
            // bin k: re row k pairs with im row 32+k (same lg,r offset, rf+2)
#pragma unroll
            for (int rf = 0; rf < 2; ++rf) {
                half4 h4;
#pragma unroll
                for (int r = 0; r < 4; ++r) {
                    float re = dacc[rf][r];
                    float im = dacc[rf + 2][r];
                    float v = (rf == 0 && r == 0)
                        ? ((lg == 0) ? log1p_fast(fabsf(re))            // bin 0
                                     : log1p_fast(sqrtf(re * re + im * im)))
                        : log1p_fast(sqrtf(re * re + im * im));
                    h4[r] = (half_t)v;
                }
                *(half4*)&Af[tl][fl * 32 + 16 * rf + 4 * lg] = h4;
            }
            if (lg == 0)   // bin 32 = |re_32| (row 32 = rf2 reg0)
                Sd[tl][60 + f] = (half_t)log1p_fast(fabsf(dacc[2][0]));
        }
        __syncthreads();   // Af / Sd ready
        // ---- GEMM1 k-chunk: k = [c*64, c*64+64) ----
        const half_t* Asrc; int astr, koff;
        if (c < 30) { Asrc = &Af[0][0]; astr = 72;  koff = 0; }
        else        { Asrc = &Sd[0][0]; astr = 136; koff = (c - 30) * 64; }
#pragma unroll
        for (int ks = 0; ks < 2; ++ks) {
            half8 af[2], bf[4];
#pragma unroll
            for (int mf = 0; mf < 2; ++mf)
                af[mf] = *(const half8*)&Asrc[(mf * 16 + lr) * astr + koff + ks * 32 + lg * 8];
#pragma unroll
            for (int nf = 0; nf < 4; ++nf) {
                int col = wv * 64 + nf * 16 + lr;
                bf[nf] = *(const half8*)&W1T[(size_t)col * KPAD + c * 64 + ks * 32 + lg * 8];
            }
#pragma unroll
            for (int mf = 0; mf < 2; ++mf)
#pragma unroll
                for (int nf = 0; nf < 4; ++nf)
                    gacc[mf][nf] = __builtin_amdgcn_mfma_f32_16x16x32_f16(af[mf], bf[nf], gacc[mf][nf], 0, 0, 0);
        }
    }

    // epilogue: bias + relu -> H1 fp16. C/D map col=lane&15, row=lg*4+r.
#pragma unroll
    for (int nf = 0; nf < 4; ++nf) {
        int col = wv * 64 + nf * 16 + lr;
        float bs = bias[col];
#pragma unroll
        for (int mf = 0; mf < 2; ++mf)
#pragma unroll
            for (int r = 0; r < 4; ++r) {
                int row = tok0 + mf * 16 + lg * 4 + r;
                H1[(size_t)row * HID + col] = (half_t)fmaxf(gacc[mf][nf][r] + bs, 0.f);
            }
    }
}

// ---------- fp16 single-product MFMA GEMM (layers 2,3) ----------
template<int BN, bool OUT_F32>
__global__ __launch_bounds__(256, 2) void gemm_f16(
        const half_t* __restrict__ A, int lda,
        const half_t* __restrict__ BT, int ldb,
        const float* __restrict__ bias,
        half_t* __restrict__ Ch, float* __restrict__ Cf,
        int N, int K) {
    constexpr int BM = 64;
    constexpr int NFR = BN / 64;
    constexpr int BUNITS = BN * 8 / 256;
    __shared__ half_t As[BM][72];
    __shared__ half_t Bs[BN][72];

    const int tid  = threadIdx.x;
    const int row0 = blockIdx.x * BM;
    const int wv = tid >> 6, lane = tid & 63;
    const int lr = lane & 15, lg = lane >> 4;

    const int arow = tid >> 2, ak = (tid & 3) * 16;
    const half_t* ap = A + (size_t)(row0 + arow) * lda + ak;

    f32x4 acc[4][NFR] = {};

    for (int k0 = 0; k0 < K; k0 += 64) {
        half8 av0 = *(const half8*)(ap + k0);
        half8 av1 = *(const half8*)(ap + k0 + 8);
        half8 bv[BUNITS];
#pragma unroll
        for (int u = 0; u < BUNITS; ++u) {
            int e = tid + u * 256;
            int n = e >> 3, c8 = (e & 7) * 8;
            bv[u] = *(const half8*)(BT + (size_t)n * ldb + k0 + c8);
        }

        __syncthreads();

        *(half8*)&As[arow][ak]     = av0;
        *(half8*)&As[arow][ak + 8] = av1;
#pragma unroll
        for (int u = 0; u < BUNITS; ++u) {
            int e = tid + u * 256;
            int n = e >> 3, c8 = (e & 7) * 8;
            *(half8*)&Bs[n][c8] = bv[u];
        }

        __syncthreads();

#pragma unroll
        for (int ks = 0; ks < 2; ++ks) {
            half8 af[4], bf[NFR];
#pragma unroll
            for (int mf = 0; mf < 4; ++mf)
                af[mf] = *(const half8*)&As[mf * 16 + lr][ks * 32 + lg * 8];
#pragma unroll
            for (int nf = 0; nf < NFR; ++nf)
                bf[nf] = *(const half8*)&Bs[wv * (16 * NFR) + nf * 16 + lr][ks * 32 + lg * 8];
#pragma unroll
            for (int mf = 0; mf < 4; ++mf)
#pragma unroll
                for (int nf = 0; nf < NFR; ++nf)
                    acc[mf][nf] = __builtin_amdgcn_mfma_f32_16x16x32_f16(af[mf], bf[nf], acc[mf][nf], 0, 0, 0);
        }
    }

#pragma unroll
    for (int nf = 0; nf < NFR; ++nf) {
        int col = wv * (16 * NFR) + nf * 16 + lr;
        float bs = bias[col];
#pragma unroll
        for (int mf = 0; mf < 4; ++mf)
#pragma unroll
            for (int r = 0; r < 4; ++r) {
                int row = row0 + mf * 16 + lg * 4 + r;
                float v = fmaxf(acc[mf][nf][r] + bs, 0.f);
                if (OUT_F32) Cf[(size_t)row * N + col] = v;
                else         Ch[(size_t)row * N + col] = (half_t)v;
            }
    }
}

// ---------- final head: [NTOK,128] @ [128,3] + b ----------
__global__ __launch_bounds__(256) void head_kernel(
        const float* __restrict__ H, const float* __restrict__ W4,
        const float* __restrict__ b4, float* __restrict__ out) {
    __shared__ float Ws[128 * 3];
    __shared__ float bs[3];
    for (int i = threadIdx.x; i < 384; i += 256) Ws[i] = W4[i];
    if (threadIdx.x < 3) bs[threadIdx.x] = b4[threadIdx.x];
    __syncthreads();
    const int tok = blockIdx.x * 256 + threadIdx.x;
    const float* h = H + (size_t)tok * 128;
    float a0 = bs[0], a1 = bs[1], a2 = bs[2];
#pragma unroll
    for (int k = 0; k < 128; ++k) {
        float hv = h[k];
        a0 = fmaf(hv, Ws[k * 3 + 0], a0);
        a1 = fmaf(hv, Ws[k * 3 + 1], a1);
        a2 = fmaf(hv, Ws[k * 3 + 2], a2);
    }
    float* o = out + (size_t)tok * 3;
    o[0] = a0; o[1] = a1; o[2] = a2;
}

extern "C" void kernel_launch(void* const* d_in, const int* in_sizes, int n_in,
                              void* d_out, int out_size, void* d_ws, size_t ws_size,
                              hipStream_t stream) {
    (void)in_sizes; (void)n_in; (void)out_size; (void)ws_size;
    const float* x  = (const float*)d_in[0];
    const float* W1 = (const float*)d_in[1];
    const float* b1 = (const float*)d_in[2];
    const float* W2 = (const float*)d_in[3];
    const float* b2 = (const float*)d_in[4];
    const float* W3 = (const float*)d_in[5];
    const float* b3 = (const float*)d_in[6];
    const float* W4 = (const float*)d_in[7];
    const float* b4 = (const float*)d_in[8];
    float* out = (float*)d_out;

    // ws layout (bytes), total ~106 MB (< 146.5 MB known-safe)
    char* w = (char*)d_ws;
    half_t* H1    = (half_t*)(w + (size_t)64 * 1024 * 1024);       // 8 MB
    half_t* W1T   = (half_t*)(w + (size_t)72 * 1024 * 1024);       // 1 MB
    half_t* W2T   = (half_t*)(w + (size_t)73 * 1024 * 1024);       // 128 KB
    half_t* W3T   = W2T + 256 * 256;                               // 64 KB
    half_t* dftH  = W3T + 128 * 256;                               // 8 KB
    half_t* xTc   = (half_t*)(w + (size_t)74 * 1024 * 1024);       // 31.7 MB
    half_t* H2    = (half_t*)(w);                                  // 8 MB
    float*  H3    = (float*) (w + (size_t)8 * 1024 * 1024);        // 8 MB

    prep_kernel<<<2448, 256, 0, stream>>>(W1, W2, W3, dftH, W1T, W2T, W3T);
    xcopy_kernel<<<240, 256, 0, stream>>>(x, xTc);

    // fused DFT + GEMM1 -> H1
    fused_fft_gemm1<<<NTOK / 32, 256, 0, stream>>>(xTc, dftH, x, W1T, b1, H1);

    // GEMM2: [16384,256] x [256,256]
    gemm_f16<256, false><<<dim3(NTOK / 64, 1), 256, 0, stream>>>(
        H1, HID, W2T, HID, b2, H2, nullptr, HID, HID);
    // GEMM3: [16384,256] x [256,128] -> fp32
    gemm_f16<128, true><<<dim3(NTOK / 64, 1), 256, 0, stream>>>(
        H2, HID, W3T, HID, b3, nullptr, H3, HID / 2, HID);

    head_kernel<<<NTOK / 256, 256, 0, stream>>>(H3, W4, b4, out);
}

// Round 10
// 107.224 us; speedup vs baseline: 5.0926x; 1.2781x over previous
//
#include <hip/hip_runtime.h>
#include <math.h>

#define T_LEN 4096
#define NF 60
#define NBINS 33
#define KPAD 2048
#define HID 256
#define NTOK 16384
#define LINE 4160    // reflected line length (mult of 8, covers c+4151 max)

typedef _Float16 half_t;
typedef half_t half8 __attribute__((ext_vector_type(8)));
typedef half_t half4 __attribute__((ext_vector_type(4)));
typedef float f32x4 __attribute__((ext_vector_type(4)));

// ---------- compile-time cos table: cos(2*pi*j/64), j=0..63 ----------
constexpr double K_PI = 3.14159265358979323846;
constexpr double tcos(double x) {
    while (x >  K_PI) x -= 2.0 * K_PI;
    while (x < -K_PI) x += 2.0 * K_PI;
    double x2 = x * x, s = 0.0, term = 1.0;
    for (int m = 0; m < 14; ++m) { s += term; term *= -x2 / ((2.0*m + 1.0) * (2.0*m + 2.0)); }
    return s;
}
struct CosTab { float v[64]; };
constexpr CosTab make_tab() {
    CosTab t{};
    for (int j = 0; j < 64; ++j) t.v[j] = (float)tcos(2.0 * K_PI * (double)j / 64.0);
    return t;
}
__device__ constexpr CosTab CTd = make_tab();

__device__ __forceinline__ float log1p_fast(float x) {
    return 0.69314718055994531f * __log2f(1.0f + x);
}

// ---------- one-time prep: fp16 DFT table + fp16 transposed weights ----------
// k-layout: k in [0,1920) = bins (f = k>>5, bin = k&31); [1920,1980) = raw
// feature k-1920; [1980,2040) = bin32 of f = k-1980; [2040,2048) = zero.
__global__ __launch_bounds__(256) void prep_kernel(
        const float* __restrict__ W1, const float* __restrict__ W2,
        const float* __restrict__ W3,
        half_t* __restrict__ dftH,
        half_t* __restrict__ W1T, half_t* __restrict__ W2T,
        half_t* __restrict__ W3T) {
    int i = blockIdx.x * 256 + threadIdx.x;
    if (i < 4096) {
        int row = i >> 6, n = i & 63;
        float c = (row < 33) ? CTd.v[(row * n) & 63]
                             : CTd.v[((row - 32) * n + 48) & 63];
        dftH[i] = (half_t)c;
        return;
    }
    i -= 4096;
    if (i < 256 * KPAD) {
        int gk = i & (KPAD - 1);
        float v = 0.f;
        if (gk < 2040) {
            int j = i >> 11;
            int r;
            if (gk < 1920) {
                int f = gk >> 5, bin = gk & 31;
                r = NF + f * NBINS + bin;                 // bins 0..31
            } else if (gk < 1980) {
                r = gk - 1920;                            // raw feature
            } else {
                r = NF + (gk - 1980) * NBINS + 32;        // bin 32
            }
            v = W1[(size_t)r * HID + j];
        }
        W1T[i] = (half_t)v;
        return;
    }
    i -= 256 * KPAD;
    if (i < 256 * 256) {
        int k = i & 255, j = i >> 8;
        W2T[i] = (half_t)W2[(size_t)k * HID + j];
        return;
    }
    i -= 256 * 256;
    if (i < 128 * 256) {
        int k = i & 255, j = i >> 8;
        W3T[i] = (half_t)W3[(size_t)k * 128 + j];
    }
}

// ---------- single reflected fp16 line per (b,f): lineG[bf][j] ----------
// lineG[bf][j] = fp16(x[b][reflect(j-32)][f]), j in [0,LINE)
__global__ __launch_bounds__(256) void xline_kernel(
        const float* __restrict__ x, half_t* __restrict__ lineG) {
    const int bf = blockIdx.x;             // 0..239
    const int b = bf / NF, f = bf - b * NF;
    const float* xb = x + (size_t)b * T_LEN * NF + f;
    half_t* L = lineG + (size_t)bf * LINE;
    for (int j = threadIdx.x; j < LINE; j += 256) {
        int s = j - 32;
        int r = (s < 0) ? -s : ((s > T_LEN - 1) ? 2 * (T_LEN - 1) - s : s);
        L[j] = (half_t)xb[(size_t)r * NF];
    }
}

// ---------- raw features + K-pad into permuted H0 rows ----------
// token t -> H0 row i = b*4096 + (t&7)*512 + ((t&4095)>>3)
__global__ __launch_bounds__(256) void raw_kernel(
        const float* __restrict__ x, half_t* __restrict__ H0) {
    const int t = blockIdx.x * 256 + threadIdx.x;   // 0..16383
    const int b = t >> 12, tl = t & (T_LEN - 1);
    const int i = (b << 12) + ((tl & 7) << 9) + (tl >> 3);
    const float* xp = x + (size_t)t * NF;
    half_t* hp = H0 + (size_t)i * KPAD;
#pragma unroll
    for (int f4 = 0; f4 < 15; ++f4) {
        float4 v = *(const float4*)(xp + f4 * 4);
        half4 h;
        h[0] = (half_t)v.x; h[1] = (half_t)v.y;
        h[2] = (half_t)v.z; h[3] = (half_t)v.w;
        *(half4*)&hp[1920 + f4 * 4] = h;
    }
    half8 z = {};
    *(half8*)&hp[2040] = z;
}

// ---------- Hankel-DFT via MFMA: one block per (b,f,phase c) ----------
// B[n][s] = line[c + 8s + n]  (tokens t = 8s+c, s in [0,512)).
// D = DFT(64x64) @ B -> 33 bins for 512 tokens, written to permuted H0 rows
// i = b*4096 + c*512 + s, cols [f*32, f*32+32) = one aligned 64B line/row.
__global__ __launch_bounds__(256) void fft_hankel(
        const half_t* __restrict__ lineG, const half_t* __restrict__ dftH,
        half_t* __restrict__ H0) {
    __shared__ half_t L[LINE];   // c-shifted line (8.3 KB)

    const int bid = blockIdx.x;        // 0..1919
    const int bf = bid >> 3, c = bid & 7;
    const int b = bf / NF, f = bf - b * NF;
    const int tid = threadIdx.x;
    const int lane = tid & 63, wv = tid >> 6;
    const int lr = lane & 15, lg = lane >> 4;

    // A fragments (8 KB table, L2-resident)
    half8 a[4][2];
#pragma unroll
    for (int rf = 0; rf < 4; ++rf)
#pragma unroll
        for (int ks = 0; ks < 2; ++ks)
            a[rf][ks] = *(const half8*)&dftH[(16 * rf + lr) * 64 + ks * 32 + lg * 8];

    // stage shifted line: L[j] = lineG[bf][c + j]  (restores 16B alignment)
    {
        const half_t* src = lineG + (size_t)bf * LINE + c;
        for (int j = tid; j < 4152; j += 256) L[j] = src[j];
    }
    __syncthreads();

    const int i0 = (b << 12) + (c << 9);   // H0 row base (s = 0)

    for (int cs = 0; cs < 8; ++cs) {
        const int s0 = wv * 128 + cs * 16;
        // B-frags: col = s0+lr, k-elem = ks*32 + lg*8 + j  -> L[8*(s0+lr)+...]
        half8 w0 = *(const half8*)&L[8 * (s0 + lr) + lg * 8];
        half8 w1 = *(const half8*)&L[8 * (s0 + lr) + 32 + lg * 8];
        f32x4 dacc[4] = {};
#pragma unroll
        for (int rf = 0; rf < 4; ++rf)
            dacc[rf] = __builtin_amdgcn_mfma_f32_16x16x32_f16(a[rf][0], w0, dacc[rf], 0, 0, 0);
#pragma unroll
        for (int rf = 0; rf < 4; ++rf)
            dacc[rf] = __builtin_amdgcn_mfma_f32_16x16x32_f16(a[rf][1], w1, dacc[rf], 0, 0, 0);

        // epilogue: D rows rf0=re0..15, rf1=re16..31, rf2=row32(re32)+im1..15,
        // rf3=im16..31. C/D: col=lane&15 (s), row-in-frag=lg*4+r.
        half_t* base = H0 + (size_t)(i0 + s0 + lr) * KPAD;
#pragma unroll
        for (int rf = 0; rf < 2; ++rf) {
            half4 h4;
#pragma unroll
            for (int r = 0; r < 4; ++r) {
                float re = dacc[rf][r];
                float im = dacc[rf + 2][r];
                float v = (rf == 0 && r == 0)
                    ? ((lg == 0) ? log1p_fast(fabsf(re))            // bin 0
                                 : log1p_fast(sqrtf(re * re + im * im)))
                    : log1p_fast(sqrtf(re * re + im * im));
                h4[r] = (half_t)v;
            }
            *(half4*)&base[f * 32 + 16 * rf + 4 * lg] = h4;
        }
        if (lg == 0)   // bin 32 = |re_32| (row 32 = rf2 reg0)
            base[1980 + f] = (half_t)log1p_fast(fabsf(dacc[2][0]));
    }
}

// ---------- fp16 single-product MFMA GEMM, N split by blockIdx.y ----------
template<int BN, bool OUT_F32>
__global__ __launch_bounds__(256, 2) void gemm_f16(
        const half_t* __restrict__ A, int lda,
        const half_t* __restrict__ BT, int ldb,
        const float* __restrict__ bias,
        half_t* __restrict__ Ch, float* __restrict__ Cf,
        int N, int K) {
    constexpr int BM = 64;
    constexpr int NFR = BN / 64;          // n-frags per wave
    constexpr int BUNITS = BN * 8 / 256;  // half8 B-units per thread
    __shared__ half_t As[BM][72];
    __shared__ half_t Bs[BN][72];

    const int tid  = threadIdx.x;
    const int row0 = blockIdx.x * BM;
    const int col0 = blockIdx.y * BN;
    const int wv = tid >> 6, lane = tid & 63;
    const int lr = lane & 15, lg = lane >> 4;

    const int arow = tid >> 2, ak = (tid & 3) * 16;
    const half_t* ap = A + (size_t)(row0 + arow) * lda + ak;

    f32x4 acc[4][NFR] = {};

    for (int k0 = 0; k0 < K; k0 += 64) {
        half8 av0 = *(const half8*)(ap + k0);
        half8 av1 = *(const half8*)(ap + k0 + 8);
        half8 bv[BUNITS];
#pragma unroll
        for (int u = 0; u < BUNITS; ++u) {
            int e = tid + u * 256;
            int n = e >> 3, c8 = (e & 7) * 8;
            bv[u] = *(const half8*)(BT + (size_t)(col0 + n) * ldb + k0 + c8);
        }

        __syncthreads();   // previous iter's frag reads done

        *(half8*)&As[arow][ak]     = av0;
        *(half8*)&As[arow][ak + 8] = av1;
#pragma unroll
        for (int u = 0; u < BUNITS; ++u) {
            int e = tid + u * 256;
            int n = e >> 3, c8 = (e & 7) * 8;
            *(half8*)&Bs[n][c8] = bv[u];
        }

        __syncthreads();   // tile staged

#pragma unroll
        for (int ks = 0; ks < 2; ++ks) {
            half8 af[4], bf[NFR];
#pragma unroll
            for (int mf = 0; mf < 4; ++mf)
                af[mf] = *(const half8*)&As[mf * 16 + lr][ks * 32 + lg * 8];
#pragma unroll
            for (int nf = 0; nf < NFR; ++nf)
                bf[nf] = *(const half8*)&Bs[wv * (16 * NFR) + nf * 16 + lr][ks * 32 + lg * 8];
#pragma unroll
            for (int mf = 0; mf < 4; ++mf)
#pragma unroll
                for (int nf = 0; nf < NFR; ++nf)
                    acc[mf][nf] = __builtin_amdgcn_mfma_f32_16x16x32_f16(af[mf], bf[nf], acc[mf][nf], 0, 0, 0);
        }
    }

    // epilogue: bias + relu; C/D map col=lane&15, row=(lane>>4)*4+reg
#pragma unroll
    for (int nf = 0; nf < NFR; ++nf) {
        int col = col0 + wv * (16 * NFR) + nf * 16 + lr;
        float bs = bias[col];
#pragma unroll
        for (int mf = 0; mf < 4; ++mf)
#pragma unroll
            for (int r = 0; r < 4; ++r) {
                int row = row0 + mf * 16 + lg * 4 + r;
                float v = fmaxf(acc[mf][nf][r] + bs, 0.f);
                if (OUT_F32) Cf[(size_t)row * N + col] = v;
                else         Ch[(size_t)row * N + col] = (half_t)v;
            }
    }
}

// ---------- final head: [NTOK,128] @ [128,3] + b, un-permute tokens ----------
__global__ __launch_bounds__(256) void head_kernel(
        const float* __restrict__ H, const float* __restrict__ W4,
        const float* __restrict__ b4, float* __restrict__ out) {
    __shared__ float Ws[128 * 3];
    __shared__ float bs[3];
    for (int i = threadIdx.x; i < 384; i += 256) Ws[i] = W4[i];
    if (threadIdx.x < 3) bs[threadIdx.x] = b4[threadIdx.x];
    __syncthreads();
    const int i = blockIdx.x * 256 + threadIdx.x;   // H row (permuted order)
    const float* h = H + (size_t)i * 128;
    float a0 = bs[0], a1 = bs[1], a2 = bs[2];
#pragma unroll
    for (int k = 0; k < 128; ++k) {
        float hv = h[k];
        a0 = fmaf(hv, Ws[k * 3 + 0], a0);
        a1 = fmaf(hv, Ws[k * 3 + 1], a1);
        a2 = fmaf(hv, Ws[k * 3 + 2], a2);
    }
    // row i -> token t = b*4096 + 8*s + c
    const int b = i >> 12, c = (i >> 9) & 7, s = i & 511;
    const int t = (b << 12) + (s << 3) + c;
    float* o = out + (size_t)t * 3;
    o[0] = a0; o[1] = a1; o[2] = a2;
}

extern "C" void kernel_launch(void* const* d_in, const int* in_sizes, int n_in,
                              void* d_out, int out_size, void* d_ws, size_t ws_size,
                              hipStream_t stream) {
    (void)in_sizes; (void)n_in; (void)out_size; (void)ws_size;
    const float* x  = (const float*)d_in[0];
    const float* W1 = (const float*)d_in[1];
    const float* b1 = (const float*)d_in[2];
    const float* W2 = (const float*)d_in[3];
    const float* b2 = (const float*)d_in[4];
    const float* W3 = (const float*)d_in[5];
    const float* b3 = (const float*)d_in[6];
    const float* W4 = (const float*)d_in[7];
    const float* b4 = (const float*)d_in[8];
    float* out = (float*)d_out;

    // ws layout (bytes), total ~92.3 MB (< 146.5 MB known-safe), no aliasing
    char* w = (char*)d_ws;
    half_t* H0    = (half_t*)(w);                                  // 64 MB
    half_t* H1    = (half_t*)(w + (size_t)64 * 1024 * 1024);       // 8 MB
    half_t* H2    = (half_t*)(w + (size_t)72 * 1024 * 1024);       // 8 MB
    float*  H3    = (float*) (w + (size_t)80 * 1024 * 1024);       // 8 MB
    half_t* W1T   = (half_t*)(w + (size_t)88 * 1024 * 1024);       // 1 MB
    half_t* W2T   = (half_t*)(w + (size_t)89 * 1024 * 1024);       // 128 KB
    half_t* W3T   = W2T + 256 * 256;                               // 64 KB
    half_t* dftH  = W3T + 128 * 256;                               // 8 KB
    half_t* lineG = (half_t*)(w + (size_t)90 * 1024 * 1024);       // 2 MB

    prep_kernel<<<2448, 256, 0, stream>>>(W1, W2, W3, dftH, W1T, W2T, W3T);
    xline_kernel<<<240, 256, 0, stream>>>(x, lineG);
    raw_kernel<<<NTOK / 256, 256, 0, stream>>>(x, H0);
    fft_hankel<<<240 * 8, 256, 0, stream>>>(lineG, dftH, H0);

    // GEMM1: [16384,2048] x [2048,256], 512 blocks (2/CU)
    gemm_f16<128, false><<<dim3(NTOK / 64, 2), 256, 0, stream>>>(
        H0, KPAD, W1T, KPAD, b1, H1, nullptr, HID, KPAD);
    // GEMM2: [16384,256] x [256,256]
    gemm_f16<128, false><<<dim3(NTOK / 64, 2), 256, 0, stream>>>(
        H1, HID, W2T, HID, b2, H2, nullptr, HID, HID);
    // GEMM3: [16384,256] x [256,128] -> fp32
    gemm_f16<64, true><<<dim3(NTOK / 64, 2), 256, 0, stream>>>(
        H2, HID, W3T, HID, b3, nullptr, H3, HID / 2, HID);

    head_kernel<<<NTOK / 256, 256, 0, stream>>>(H3, W4, b4, out);
}